// Round 4
// baseline (306.840 us; speedup 1.0000x reference)
//
#include <hip/hip_runtime.h>

// Problem: latent (16,192,64,64) fp32, codebook (1024,192) fp32.
// N = 65536 points, D = 192, K = 1024.
// d_out = [quantized: 12582912 fp32][indices-as-float: 65536].

#define NPTS   65536
#define DIMS   192
#define KCB    1024
#define HW     4096
#define QELEMS 12582912

typedef __attribute__((ext_vector_type(8))) _Float16 f16x8;
typedef __attribute__((ext_vector_type(4))) float f32x4;

// ============================ f16 MFMA path =============================
// Codebook rows are unit-normalized -> argmin dist == argmax dot, and since
// inv_norm(x) > 0 is per-point, argmax(inv*dot) == argmax(dot): rank RAW dots.
// q = trunc(fma(dot_raw, 2^16, 2^21)). If the true fp32 winner differs from
// the f16 pick, q_b - q_s <= 128*||x|| + 2 (4u dot error + c2 jitter + trunc),
// so flagging (q_b - q_s) < 152*||x|| + 4 guarantees rescore repairs it.
// Flagged points get exact fp32 batched rescore.
//
// B path (round-4): NO LDS staging. Bpf is 384 KB, L2-resident; chunk-major
// layout makes each wave's fragment load a contiguous, fully-coalesced 1 KB
// global read. 3-deep register ring (prefetch distance 2 phases ~ 2x L2
// latency) hides latency with zero barriers in the K-loop.

// running top-2 under MAX: b >= s; merge sorted pair (ob >= os).
__device__ __forceinline__ void top2_merge_max(unsigned& b, unsigned& s,
                                               unsigned ob, unsigned os) {
    unsigned nb = max(b, ob);
    unsigned ns = max(min(b, ob), max(s, os));
    b = nb; s = ns;
}

// ---- fused prep: cbk -> {Bpf f16 chunk-major, cbkT, c2}; zeroes cnt ----
// grid 16 x 256; block handles 64 codewords staged once in LDS.
__global__ __launch_bounds__(256) void k_prep(const float* __restrict__ cbk,
                                              _Float16* __restrict__ Bpf,
                                              float* __restrict__ cbkT,
                                              float* __restrict__ c2,
                                              int* __restrict__ cnt) {
    __shared__ float q[64 * 193];
    const int tid = threadIdx.x;
    const int k0 = blockIdx.x * 64;
    const int lane = tid & 63;
    const int grp = tid >> 6;
    if (blockIdx.x == 0 && tid == 0) *cnt = 0;
    for (int r = grp; r < 64; r += 4) {
        const float* row = cbk + (size_t)(k0 + r) * DIMS;
        for (int c = lane; c < DIMS; c += 64) q[r * 193 + c] = row[c];
    }
    __syncthreads();
    // fp32 transpose for rescore
    for (int d = grp; d < DIMS; d += 4)
        cbkT[(size_t)d * KCB + k0 + lane] = q[lane * 193 + d];
    // f16 chunk-major [c][k][32]
    for (int r = grp; r < 64; r += 4)
        for (int c = lane; c < DIMS; c += 64)
            Bpf[((size_t)(c >> 5) * KCB + k0 + r) * 32 + (c & 31)] =
                (_Float16)q[r * 193 + c];
    // row squared norms
    if (tid < 64) {
        float s = 0.f;
        #pragma unroll 4
        for (int c = 0; c < DIMS; ++c) {
            float v = q[tid * 193 + c];
            s = fmaf(v, v, s);
        }
        c2[k0 + tid] = s;
    }
}

// ---- fused: global->reg A frags + direct-global B frags + MFMA + argmax +
//      gather ----
// grid 512 x 256 thr (4 waves); wave owns 32 points x all 1024 codewords.
// af[6][2] (48 VGPR) from coalesced global loads; bf[3][4] register ring
// prefetched 2 phases ahead (96 phases = 16 strips x 6 chunks, 8 MFMA each).
// No barriers, no LDS, no vmcnt games in the K-loop.
__global__ __launch_bounds__(256, 2) void k_gemm_f(const float* __restrict__ latent,
                                                   const _Float16* __restrict__ Bpf,
                                                   const float* __restrict__ cbk,
                                                   float* __restrict__ out_q,
                                                   float* __restrict__ idxf,
                                                   int* __restrict__ list,
                                                   int* __restrict__ cnt) {
    __shared__ int sidx[128];
    __shared__ float qg[16 * 193];              // gather staging (12.4 KB)

    const int tid = threadIdx.x;
    const int wave = tid >> 6;
    const int lane = tid & 63;
    const int quad = lane >> 4;
    const int l15 = lane & 15;
    const int n0 = blockIdx.x * 128;
    const int bB = n0 >> 12;
    const int hw0 = (n0 & 4095) + wave * 32;
    const size_t latb = (size_t)bB * DIMS * HW;

    // ---- A fragments + per-point norms ----
    // af[c][mt]: point hw0+mt*16+l15, dims c*32+quad*8 .. +7
    f16x8 af[6][2];
    float nrm[2];
    {
        float ssq0 = 0.f, ssq1 = 0.f;
        #pragma unroll
        for (int c = 0; c < 6; ++c) {
            #pragma unroll
            for (int mt = 0; mt < 2; ++mt) {
                const float* lp = latent + latb + (size_t)(c * 32 + quad * 8) * HW
                                  + hw0 + mt * 16 + l15;
                float v[8];
                #pragma unroll
                for (int j = 0; j < 8; ++j) v[j] = lp[(size_t)j * HW];
                float s = 0.f;
                #pragma unroll
                for (int j = 0; j < 8; ++j) s = fmaf(v[j], v[j], s);
                if (mt == 0) ssq0 += s; else ssq1 += s;
                f16x8 h;
                #pragma unroll
                for (int j = 0; j < 8; ++j) h[j] = (_Float16)v[j];
                af[c][mt] = h;
            }
        }
        // sum across the 4 quad-lanes holding the same point (xor bits 4,5)
        ssq0 += __shfl_xor(ssq0, 16, 64); ssq0 += __shfl_xor(ssq0, 32, 64);
        ssq1 += __shfl_xor(ssq1, 16, 64); ssq1 += __shfl_xor(ssq1, 32, 64);
        nrm[0] = sqrtf(ssq0); nrm[1] = sqrtf(ssq1);
    }

    // per-lane B base: codeword l15, dims quad*8 within chunk
    const _Float16* bp0 = Bpf + (size_t)l15 * 32 + quad * 8;
    // offset(S strip, C chunk) = C*KCB*32 + S*64*32 elements; nt adds nt*512

    f16x8 bf[3][4];
    #pragma unroll
    for (int nt = 0; nt < 4; ++nt) {            // (ss=0, c=0) -> bf[0]
        bf[0][nt] = *(const f16x8*)(bp0 + (size_t)nt * 512);
    }
    #pragma unroll
    for (int nt = 0; nt < 4; ++nt) {            // (ss=0, c=1) -> bf[1]
        bf[1][nt] = *(const f16x8*)(bp0 + (size_t)KCB * 32 + nt * 512);
    }

    unsigned rb[8], rs[8];
    #pragma unroll
    for (int i = 0; i < 8; ++i) { rb[i] = 0u; rs[i] = 0u; }

    // ---- K-loop: 16 strips (64 k) x 6 chunks (32 dims) = 96 phases ----
    for (int ss = 0; ss < 16; ++ss) {
        f32x4 acc[2][4];
        #pragma unroll
        for (int c = 0; c < 6; ++c) {
            // prefetch phase +2 into bf[(c+2)%3]
            const bool last = (ss == 15) && (c >= 4);
            if (!last) {
                const int nss = (c >= 4) ? ss + 1 : ss;
                const int ncc = (c >= 4) ? c - 4 : c + 2;
                const _Float16* p =
                    bp0 + ((size_t)ncc * KCB + (size_t)nss * 64) * 32;
                #pragma unroll
                for (int nt = 0; nt < 4; ++nt)
                    bf[(c + 2) % 3][nt] = *(const f16x8*)(p + (size_t)nt * 512);
            }
            // compute chunk c with bf[c%3]
            if (c == 0) {
                #pragma unroll
                for (int mt = 0; mt < 2; ++mt)
                    #pragma unroll
                    for (int nt = 0; nt < 4; ++nt)
                        acc[mt][nt] = __builtin_amdgcn_mfma_f32_16x16x32_f16(
                            af[0][mt], bf[0][nt],
                            (f32x4){0.f, 0.f, 0.f, 0.f}, 0, 0, 0);
            } else {
                #pragma unroll
                for (int mt = 0; mt < 2; ++mt)
                    #pragma unroll
                    for (int nt = 0; nt < 4; ++nt)
                        acc[mt][nt] = __builtin_amdgcn_mfma_f32_16x16x32_f16(
                            af[c][mt], bf[c % 3][nt], acc[mt][nt], 0, 0, 0);
            }
        }
        // strip epilogue: quantize raw dots (fixed scale), top-2 merge
        const int kb = ss * 64 + l15;
        #pragma unroll
        for (int mt = 0; mt < 2; ++mt) {
            #pragma unroll
            for (int r = 0; r < 4; ++r) {
                unsigned p0 = ((unsigned)fmaf(acc[mt][0][r], 65536.f, 2097152.f) << 10) | (unsigned)(kb);
                unsigned p1 = ((unsigned)fmaf(acc[mt][1][r], 65536.f, 2097152.f) << 10) | (unsigned)(kb + 16);
                unsigned p2 = ((unsigned)fmaf(acc[mt][2][r], 65536.f, 2097152.f) << 10) | (unsigned)(kb + 32);
                unsigned p3 = ((unsigned)fmaf(acc[mt][3][r], 65536.f, 2097152.f) << 10) | (unsigned)(kb + 48);
                unsigned b01 = max(p0, p1), s01 = min(p0, p1);
                unsigned b23 = max(p2, p3), s23 = min(p2, p3);
                unsigned bb = max(b01, b23);
                unsigned s4 = max(min(b01, b23), max(s01, s23));
                top2_merge_max(rb[mt * 4 + r], rs[mt * 4 + r], bb, s4);
            }
        }
    }

    // ---- cross-l15 merge + per-point finalize (wave-local) ----
    const int pw = wave * 32;
    #pragma unroll
    for (int i = 0; i < 8; ++i) {
        unsigned b = rb[i], s = rs[i];
        #pragma unroll
        for (int off = 1; off < 16; off <<= 1) {
            unsigned ob = __shfl_xor(b, off, 64);
            unsigned os = __shfl_xor(s, off, 64);
            top2_merge_max(b, s, ob, os);
        }
        const int mt = i >> 2, r = i & 3;
        // norm of point row quad*4+r lives at lane quad*16 + quad*4 + r
        float nv = __shfl(nrm[mt], (lane & 48) + ((lane >> 4) << 2) + r, 64);
        if (l15 == 0) {
            int ploc = pw + mt * 16 + ((lane >> 4) << 2) + r;
            int k = (int)(b & 1023u);
            sidx[ploc] = k;
            idxf[n0 + ploc] = (float)k;
            unsigned Mq = (unsigned)fmaf(152.0f, nv, 4.0f);
            if (((b >> 10) - (s >> 10)) < Mq) {
                int pos = atomicAdd(cnt, 1);
                list[pos] = n0 + ploc;
            }
        }
    }

    __syncthreads();                        // sidx visible

    // ---- gather epilogue ----
    for (int chk = 0; chk < 8; ++chk) {
        int p0c = chk * 16;
        for (int r = wave; r < 16; r += 4) {
            const float* row = cbk + (size_t)sidx[p0c + r] * DIMS;
            for (int c = lane; c < DIMS; c += 64) qg[r * 193 + c] = row[c];
        }
        __syncthreads();
        float* ob = out_q + latb + (n0 & 4095) + p0c;
        #pragma unroll
        for (int i = 0; i < 12; ++i) {
            int u = i * 256 + tid;
            int c = u >> 4, p = u & 15;
            ob[(size_t)c * HW + p] = qg[p * 193 + c];
        }
        __syncthreads();
    }
}

// ---- batched exact fp32 rescore: 16 flagged points per block ----
__global__ __launch_bounds__(256) void k_rescore16(const float* __restrict__ latent,
                                                   const float* __restrict__ cbkT,
                                                   const float* __restrict__ cbk,
                                                   const float* __restrict__ c2,
                                                   const int* __restrict__ list,
                                                   const int* __restrict__ cnt,
                                                   float* __restrict__ out_q,
                                                   float* __restrict__ idxf) {
    __shared__ float xs[16][200];
    __shared__ float part[16][16];
    __shared__ float inv_s[16];
    __shared__ unsigned long long best[16];
    const int tid = threadIdx.x;
    const int count = *cnt;
    const float4* ct = (const float4*)cbkT;     // [d][256] float4
    const int j = tid >> 4, dl = tid & 15;

    for (int base = blockIdx.x * 16; base < count; base += gridDim.x * 16) {
        __syncthreads();                        // guard xs/best reuse
        float ss = 0.f;
        int n = 0, bb = 0, hw = 0;
        bool valid = (base + j) < count;
        if (valid) {
            n = list[base + j]; bb = n >> 12; hw = n & 4095;
            #pragma unroll
            for (int i = 0; i < 12; ++i) {
                int d = dl + i * 16;
                float v = latent[((size_t)bb * DIMS + d) * HW + hw];
                xs[j][d] = v;
                ss = fmaf(v, v, ss);
            }
        }
        part[j][dl] = ss;
        if (tid < 16) best[tid] = ~0ull;
        __syncthreads();
        if (tid < 16) {
            float s = 0.f;
            #pragma unroll
            for (int i = 0; i < 16; ++i) s += part[tid][i];
            inv_s[tid] = 1.0f / (sqrtf(s) + 1e-8f);
        }
        __syncthreads();

        // dots: thread owns codewords 4*tid..4*tid+3 for all 16 points
        float4 a[16];
        #pragma unroll
        for (int p = 0; p < 16; ++p) a[p] = make_float4(0.f, 0.f, 0.f, 0.f);
        for (int d = 0; d < DIMS; d += 4) {
            float4 cv0 = ct[(size_t)(d + 0) * 256 + tid];
            float4 cv1 = ct[(size_t)(d + 1) * 256 + tid];
            float4 cv2 = ct[(size_t)(d + 2) * 256 + tid];
            float4 cv3 = ct[(size_t)(d + 3) * 256 + tid];
            #pragma unroll
            for (int p = 0; p < 16; ++p) {
                float4 xv = *(const float4*)&xs[p][d];
                a[p].x = fmaf(xv.x, cv0.x, a[p].x); a[p].y = fmaf(xv.x, cv0.y, a[p].y);
                a[p].z = fmaf(xv.x, cv0.z, a[p].z); a[p].w = fmaf(xv.x, cv0.w, a[p].w);
                a[p].x = fmaf(xv.y, cv1.x, a[p].x); a[p].y = fmaf(xv.y, cv1.y, a[p].y);
                a[p].z = fmaf(xv.y, cv1.z, a[p].z); a[p].w = fmaf(xv.y, cv1.w, a[p].w);
                a[p].x = fmaf(xv.z, cv2.x, a[p].x); a[p].y = fmaf(xv.z, cv2.y, a[p].y);
                a[p].z = fmaf(xv.z, cv2.z, a[p].z); a[p].w = fmaf(xv.z, cv2.w, a[p].w);
                a[p].x = fmaf(xv.w, cv3.x, a[p].x); a[p].y = fmaf(xv.w, cv3.y, a[p].y);
                a[p].z = fmaf(xv.w, cv3.z, a[p].z); a[p].w = fmaf(xv.w, cv3.w, a[p].w);
            }
        }
        #pragma unroll
        for (int p = 0; p < 16; ++p) {
            float inv = inv_s[p];
            float dot4[4] = {a[p].x, a[p].y, a[p].z, a[p].w};
            unsigned long long loc = ~0ull;
            #pragma unroll
            for (int e = 0; e < 4; ++e) {
                int k = 4 * tid + e;
                float dist = c2[k] - 2.f * inv * dot4[e];
                unsigned ub = __float_as_uint(dist);
                ub ^= (ub >> 31) ? 0xFFFFFFFFu : 0x80000000u;   // monotonic
                unsigned long long pk =
                    ((unsigned long long)ub << 32) | (unsigned)k;
                loc = loc < pk ? loc : pk;
            }
            #pragma unroll
            for (int off = 1; off < 64; off <<= 1) {
                unsigned long long o = __shfl_xor(loc, off, 64);
                loc = loc < o ? loc : o;
            }
            if ((tid & 63) == 0) atomicMin(&best[p], loc);
        }
        __syncthreads();
        if (valid) {
            int kk = (int)(best[j] & 0xFFFFFFFFull);
            #pragma unroll
            for (int i = 0; i < 12; ++i) {
                int d = dl + i * 16;
                out_q[((size_t)bb * DIMS + d) * HW + hw] = cbk[(size_t)kk * DIMS + d];
            }
            if (dl == 0) idxf[n] = (float)kk;
        }
    }
}

// ======================= fallback fp32 path (round-1) ====================
__global__ __launch_bounds__(256) void k_norms_fb(const float* __restrict__ latent,
                                                  float* __restrict__ inv_norm) {
    __shared__ float red[256];
    const int tid = threadIdx.x;
    const int n0 = blockIdx.x * 128;
    const int nl = tid & 127;
    const int half = tid >> 7;
    const int b = n0 >> 12;
    const int hw = (n0 & 4095) + nl;
    const float* base = latent + (size_t)b * DIMS * HW + hw;
    float ssq = 0.f;
    for (int c = half; c < DIMS; c += 2) {
        float v = base[(size_t)c * HW];
        ssq = fmaf(v, v, ssq);
    }
    red[tid] = ssq;
    __syncthreads();
    if (half == 0) {
        float s = red[tid] + red[tid + 128];
        inv_norm[n0 + nl] = 1.0f / (sqrtf(s) + 1e-8f);
    }
}

__global__ __launch_bounds__(256) void k_c2_fb(const float* __restrict__ cbk,
                                               float* __restrict__ c2) {
    int k = blockIdx.x * 256 + threadIdx.x;
    if (k >= KCB) return;
    const float4* row = (const float4*)(cbk + (size_t)k * DIMS);
    float s = 0.f;
    #pragma unroll
    for (int i = 0; i < DIMS / 4; ++i) {
        float4 v = row[i];
        s += v.x * v.x + v.y * v.y + v.z * v.z + v.w * v.w;
    }
    c2[k] = s;
}

#define LDX  132
__global__ __launch_bounds__(256) void k_dist_fb(const float* __restrict__ latent,
                                                 const float* __restrict__ cbk,
                                                 const float* __restrict__ inv_norm,
                                                 const float* __restrict__ c2,
                                                 int* __restrict__ idx_out,
                                                 float* __restrict__ idxf_out) {
    __shared__ __align__(16) float xsm[64 * LDX];
    __shared__ __align__(16) float csm[64 * LDX];
    __shared__ unsigned long long red[128];
    const int tid = threadIdx.x;
    const int n0 = blockIdx.x * 128;
    const int b = n0 >> 12;
    const int hw0 = n0 & 4095;
    const int kt = tid & 15;
    const int mt = tid >> 4;
    const float* lat_base = latent + (size_t)b * DIMS * HW + hw0;
    float inv[8];
    #pragma unroll
    for (int i = 0; i < 8; ++i) inv[i] = inv_norm[n0 + mt * 8 + i];
    float best[8];
    int bidx[8];
    #pragma unroll
    for (int i = 0; i < 8; ++i) { best[i] = 3.4e38f; bidx[i] = 0; }
    const int nl = tid & 127;
    const int cp = tid >> 7;
    for (int k0 = 0; k0 < KCB; k0 += 128) {
        float acc[8][8];
        #pragma unroll
        for (int i = 0; i < 8; ++i)
            #pragma unroll
            for (int j = 0; j < 8; ++j) acc[i][j] = 0.f;
        for (int d0 = 0; d0 < DIMS; d0 += 64) {
            __syncthreads();
            for (int cc = cp; cc < 64; cc += 2)
                xsm[cc * LDX + nl] = lat_base[(size_t)(d0 + cc) * HW + nl];
            #pragma unroll
            for (int i = 0; i < 8; ++i) {
                int f4 = tid + 256 * i;
                int kk = f4 >> 4;
                int dq = f4 & 15;
                float4 v = *(const float4*)(cbk + (size_t)(k0 + kk) * DIMS + d0 + dq * 4);
                csm[(dq * 4 + 0) * LDX + kk] = v.x;
                csm[(dq * 4 + 1) * LDX + kk] = v.y;
                csm[(dq * 4 + 2) * LDX + kk] = v.z;
                csm[(dq * 4 + 3) * LDX + kk] = v.w;
            }
            __syncthreads();
            for (int d = 0; d < 64; ++d) {
                const float* xr = &xsm[d * LDX + mt * 8];
                const float* cr = &csm[d * LDX + kt * 8];
                float x8[8], c8[8];
                *(float4*)&x8[0] = *(const float4*)&xr[0];
                *(float4*)&x8[4] = *(const float4*)&xr[4];
                *(float4*)&c8[0] = *(const float4*)&cr[0];
                *(float4*)&c8[4] = *(const float4*)&cr[4];
                #pragma unroll
                for (int i = 0; i < 8; ++i)
                    #pragma unroll
                    for (int j = 0; j < 8; ++j)
                        acc[i][j] = fmaf(x8[i], c8[j], acc[i][j]);
            }
        }
        float cc2[8];
        #pragma unroll
        for (int j = 0; j < 8; ++j) cc2[j] = c2[k0 + kt * 8 + j];
        #pragma unroll
        for (int i = 0; i < 8; ++i)
            #pragma unroll
            for (int j = 0; j < 8; ++j) {
                float t = inv[i] * acc[i][j];
                float dist = fmaf(-2.f, t, cc2[j]);
                int kidx = k0 + kt * 8 + j;
                if (dist < best[i]) { best[i] = dist; bidx[i] = kidx; }
            }
    }
    if (tid < 128) red[tid] = ~0ull;
    __syncthreads();
    #pragma unroll
    for (int i = 0; i < 8; ++i) {
        unsigned long long p =
            ((unsigned long long)__float_as_uint(best[i]) << 32) | (unsigned)bidx[i];
        atomicMin(&red[mt * 8 + i], p);
    }
    __syncthreads();
    if (tid < 128) {
        int k = (int)(red[tid] & 0xFFFFFFFFu);
        idx_out[n0 + tid] = k;
        idxf_out[n0 + tid] = (float)k;
    }
}

__global__ __launch_bounds__(256) void k_gather(const float* __restrict__ cbk,
                                                const int* __restrict__ idx,
                                                float* __restrict__ out) {
    __shared__ float q[64 * 193];
    __shared__ int sidx[64];
    const int tid = threadIdx.x;
    const int n0 = blockIdx.x * 64;
    const int b = n0 >> 12;
    const int hw0 = n0 & 4095;
    const int lane = tid & 63;
    const int grp = tid >> 6;

    if (tid < 64) sidx[tid] = idx[n0 + tid];
    __syncthreads();
    for (int r = grp; r < 64; r += 4) {
        const float* row = cbk + (size_t)sidx[r] * DIMS;
        for (int c = lane; c < DIMS; c += 64) q[r * 193 + c] = row[c];
    }
    __syncthreads();
    float* obase = out + (size_t)b * DIMS * HW + hw0;
    for (int c = grp; c < DIMS; c += 4) {
        obase[(size_t)c * HW + lane] = q[lane * 193 + c];
    }
}

// ================================ launch ================================
extern "C" void kernel_launch(void* const* d_in, const int* in_sizes, int n_in,
                              void* d_out, int out_size, void* d_ws, size_t ws_size,
                              hipStream_t stream) {
    const float* latent = (const float*)d_in[0];
    const float* cbk = (const float*)d_in[1];
    float* out = (float*)d_out;
    float* out_q = out;
    float* out_idx = out + QELEMS;

    if (ws_size >= 2u * 1024u * 1024u) {
        // ws layout (bytes):
        char* w = (char*)d_ws;
        _Float16* Bpf = (_Float16*)w;                          //    393,216
        float* cbkT = (float*)(w + 393216);                    //    786,432
        float* c2 = (float*)(w + 1179648);                     //      4,096
        int* list = (int*)(w + 1183744);                       //    262,144
        int* cnt = (int*)(w + 1445888);                        //          4

        k_prep<<<KCB / 64, 256, 0, stream>>>(cbk, Bpf, cbkT, c2, cnt);
        k_gemm_f<<<512, 256, 0, stream>>>(latent, Bpf, cbk, out_q, out_idx,
                                          list, cnt);
        k_rescore16<<<512, 256, 0, stream>>>(latent, cbkT, cbk, c2, list, cnt,
                                             out_q, out_idx);
    } else {
        float* inv_norm = (float*)d_ws;
        float* c2 = inv_norm + NPTS;
        int* idx = (int*)(c2 + KCB);
        k_norms_fb<<<NPTS / 128, 256, 0, stream>>>(latent, inv_norm);
        k_c2_fb<<<4, 256, 0, stream>>>(cbk, c2);
        k_dist_fb<<<NPTS / 128, 256, 0, stream>>>(latent, cbk, inv_norm, c2, idx, out_idx);
        k_gather<<<NPTS / 64, 256, 0, stream>>>(cbk, idx, out_q);
    }
}

// Round 5
// 243.911 us; speedup vs baseline: 1.2580x; 1.2580x over previous
//
#include <hip/hip_runtime.h>

// Problem: latent (16,192,64,64) fp32, codebook (1024,192) fp32.
// N = 65536 points, D = 192, K = 1024.
// d_out = [quantized: 12582912 fp32][indices-as-float: 65536].

#define NPTS   65536
#define DIMS   192
#define KCB    1024
#define HW     4096
#define QELEMS 12582912

typedef __attribute__((ext_vector_type(8))) _Float16 f16x8;
typedef __attribute__((ext_vector_type(4))) _Float16 f16x4;
typedef __attribute__((ext_vector_type(4))) float f32x4;

// ============================ f16 MFMA path =============================
// Codebook rows are unit-normalized -> argmin dist == argmax dot; inv_norm>0
// per point -> rank RAW dots. q = trunc(fma(dot_raw, 2^16, 2^21)). If the
// true fp32 winner differs from the f16 pick, q_b - q_s <= 128*||x|| + 2,
// so flagging (q_b - q_s) < 152*||x|| + 4 guarantees the exact fp32 rescore
// (fused, block-local) repairs it. Verified rounds 3/4 (absmax 0).

__device__ __forceinline__ void async_load16(const void* g, void* l) {
    __builtin_amdgcn_global_load_lds(
        (const __attribute__((address_space(1))) unsigned int*)g,
        (__attribute__((address_space(3))) unsigned int*)l, 16, 0, 0);
}

// running top-2 under MAX: b >= s; merge sorted pair (ob >= os).
__device__ __forceinline__ void top2_merge_max(unsigned& b, unsigned& s,
                                               unsigned ob, unsigned os) {
    unsigned nb = max(b, ob);
    unsigned ns = max(min(b, ob), max(s, os));
    b = nb; s = ns;
}

// ---- fused prep: cbk -> {Bpf f16 group-major [g][k][64], cbkT, c2} ----
// grid 16 x 256; block handles 64 codewords staged once in LDS.
__global__ __launch_bounds__(256) void k_prep(const float* __restrict__ cbk,
                                              _Float16* __restrict__ Bpf,
                                              float* __restrict__ cbkT,
                                              float* __restrict__ c2) {
    __shared__ float q[64 * 193];
    const int tid = threadIdx.x;
    const int k0 = blockIdx.x * 64;
    const int lane = tid & 63;
    const int grp = tid >> 6;
    for (int r = grp; r < 64; r += 4) {
        const float* row = cbk + (size_t)(k0 + r) * DIMS;
        for (int c = lane; c < DIMS; c += 64) q[r * 193 + c] = row[c];
    }
    __syncthreads();
    // fp32 transpose for rescore
    for (int d = grp; d < DIMS; d += 4)
        cbkT[(size_t)d * KCB + k0 + lane] = q[lane * 193 + d];
    // f16 group-major [g][k][64] (g = dims g*64..g*64+63)
    for (int r = grp; r < 64; r += 4)
        for (int c = lane; c < DIMS; c += 64)
            Bpf[((size_t)(c >> 6) * KCB + k0 + r) * 64 + (c & 63)] =
                (_Float16)q[r * 193 + c];
    // row squared norms
    if (tid < 64) {
        float s = 0.f;
        #pragma unroll 4
        for (int c = 0; c < DIMS; ++c) {
            float v = q[tid * 193 + c];
            s = fmaf(v, v, s);
        }
        c2[k0 + tid] = s;
    }
}

// ---- fused: latent->f16 LDS slab + MFMA GEMM + argmax + in-block exact
//      rescore + gather (round-0 proven structure + fused tail) ----
// grid 512 (128 points each); 4 waves = 2x2 of 64x64 MFMA tiles.
__global__ __launch_bounds__(256, 2) void k_gemm_f(const float* __restrict__ latent,
                                                   const _Float16* __restrict__ Bpf,
                                                   const float* __restrict__ cbkT,
                                                   const float* __restrict__ c2,
                                                   const float* __restrict__ cbk,
                                                   float* __restrict__ out_q,
                                                   float* __restrict__ idxf) {
    __shared__ __align__(16) _Float16 As[128 * 200];   // 51200 B (xs/gather overlay)
    __shared__ __align__(16) _Float16 Bs[128 * 64];    // 16384 B
    __shared__ float nrm_s[128];
    __shared__ uint2 t2buf[256];
    __shared__ int sidx[128];
    __shared__ int slist[128];
    __shared__ int scnt;
    __shared__ float part16[16][16];
    __shared__ float inv16[16];
    __shared__ unsigned long long best16[16];

    const int tid = threadIdx.x;
    const int wave = tid >> 6;
    const int lane = tid & 63;
    const int quad = lane >> 4;
    const int l15 = lane & 15;
    const int wm = (wave >> 1) * 64;
    const int wn = (wave & 1) * 64;
    const int n0 = blockIdx.x * 128;
    const int bB = n0 >> 12;
    const int hw0 = n0 & 4095;
    const size_t latb = (size_t)bB * DIMS * HW;

    // ---- phase 0: load raw latent slab once, f16-convert, ssq ----
    {
        float* part = (float*)Bs;               // overlay (pre-K-loop)
        const float* lat = latent + latb + hw0;
        const int p = tid & 127, ch = tid >> 7;
        float ss = 0.f;
        #pragma unroll 4
        for (int i = 0; i < 24; ++i) {
            int c0 = i * 8 + ch * 4;
            float v0 = lat[(size_t)(c0 + 0) * HW + p];
            float v1 = lat[(size_t)(c0 + 1) * HW + p];
            float v2 = lat[(size_t)(c0 + 2) * HW + p];
            float v3 = lat[(size_t)(c0 + 3) * HW + p];
            ss = fmaf(v0, v0, fmaf(v1, v1, fmaf(v2, v2, fmaf(v3, v3, ss))));
            f16x4 h = { (_Float16)v0, (_Float16)v1, (_Float16)v2, (_Float16)v3 };
            *(f16x4*)&As[p * 200 + c0] = h;
        }
        part[ch * 128 + p] = ss;
        __syncthreads();
        if (tid < 128)
            nrm_s[tid] = sqrtf(part[tid] + part[128 + tid]);
        if (tid == 0) scnt = 0;
        __syncthreads();                        // part consumed before Bs reuse
    }

    unsigned rb[16], rs[16];
    #pragma unroll
    for (int i = 0; i < 16; ++i) { rb[i] = 0u; rs[i] = 0u; }

    // ---- K-loop: nb (8 codeword strips) x g (3 dim groups) ----
    for (int nb = 0; nb < 8; ++nb) {
        f32x4 acc[4][4];
        #pragma unroll
        for (int mt = 0; mt < 4; ++mt)
            #pragma unroll
            for (int nt = 0; nt < 4; ++nt)
                #pragma unroll
                for (int r = 0; r < 4; ++r) acc[mt][nt][r] = 0.f;

        for (int g = 0; g < 3; ++g) {
            __syncthreads();
            #pragma unroll
            for (int i = 0; i < 4; ++i) {
                int u = i * 256 + tid;          // 1024 16B-units
                int m = u >> 3, c = u & 7;
                int sw = c ^ (m & 7);           // XOR swizzle
                async_load16(Bpf + (((size_t)g * KCB + nb * 128 + m) * 8 + sw) * 8,
                             &Bs[u * 8]);
            }
            asm volatile("s_waitcnt vmcnt(0)" ::: "memory");
            __syncthreads();
            #pragma unroll
            for (int s = 0; s < 2; ++s) {
                f16x8 af[4], bfr[4];
                #pragma unroll
                for (int mt = 0; mt < 4; ++mt) {
                    int m = wm + mt * 16 + l15;
                    af[mt] = *(const f16x8*)&As[m * 200 + g * 64 + s * 32 + quad * 8];
                }
                #pragma unroll
                for (int nt = 0; nt < 4; ++nt) {
                    int n = wn + nt * 16 + l15;
                    int c = (s * 4 + quad) ^ (n & 7);
                    bfr[nt] = *(const f16x8*)&Bs[n * 64 + c * 8];
                }
                #pragma unroll
                for (int mt = 0; mt < 4; ++mt)
                    #pragma unroll
                    for (int nt = 0; nt < 4; ++nt)
                        acc[mt][nt] = __builtin_amdgcn_mfma_f32_16x16x32_f16(
                            af[mt], bfr[nt], acc[mt][nt], 0, 0, 0);
            }
        }

        // per-nb epilogue: quantize RAW dots (fixed scale); top-2 merge
        int kbase = nb * 128 + wn;
        #pragma unroll
        for (int mt = 0; mt < 4; ++mt) {
            #pragma unroll
            for (int r = 0; r < 4; ++r) {
                unsigned p[4];
                #pragma unroll
                for (int nt = 0; nt < 4; ++nt) {
                    p[nt] = ((unsigned)fmaf(acc[mt][nt][r], 65536.f, 2097152.f) << 10)
                            | (unsigned)(kbase + nt * 16 + l15);
                }
                unsigned b01 = max(p[0], p[1]), s01 = min(p[0], p[1]);
                unsigned b23 = max(p[2], p[3]), s23 = min(p[2], p[3]);
                unsigned bb = max(b01, b23);
                unsigned s4 = max(min(b01, b23), max(s01, s23));
                top2_merge_max(rb[mt * 4 + r], rs[mt * 4 + r], bb, s4);
            }
        }
    }

    // ---- cross-lane / cross-wave top-2 merge ----
    __syncthreads();
    #pragma unroll
    for (int i = 0; i < 16; ++i) {
        unsigned b = rb[i], s = rs[i];
        #pragma unroll
        for (int off = 1; off < 16; off <<= 1) {
            unsigned ob = __shfl_xor(b, off, 64);
            unsigned os = __shfl_xor(s, off, 64);
            top2_merge_max(b, s, ob, os);
        }
        if (l15 == 0) {
            int mt = i >> 2, r = i & 3;
            int mloc = wm + mt * 16 + quad * 4 + r;
            t2buf[mloc * 2 + (wave & 1)] = make_uint2(b, s);
        }
    }
    __syncthreads();
    if (tid < 128) {
        uint2 x = t2buf[tid * 2];
        uint2 y = t2buf[tid * 2 + 1];
        unsigned b = x.x, s = x.y;
        top2_merge_max(b, s, y.x, y.y);
        sidx[tid] = (int)(b & 1023u);
        unsigned Mq = (unsigned)fmaf(152.0f, nrm_s[tid], 4.0f);
        if (((b >> 10) - (s >> 10)) < Mq) {
            int pos = atomicAdd(&scnt, 1);
            slist[pos] = tid;
        }
    }
    __syncthreads();

    // ---- fused exact fp32 rescore of flagged points (block-local) ----
    {
        const int scnt_v = scnt;
        float* xsf = (float*)As;                // xs[16][200] overlay (12.8 KB)
        const float4* ct = (const float4*)cbkT; // [d][256] float4
        const int j = tid >> 4, dl = tid & 15;
        for (int base = 0; base < scnt_v; base += 16) {
            const bool valid = (base + j) < scnt_v;
            const int ploc = valid ? slist[base + j] : 0;
            float ss = 0.f;
            if (valid) {
                #pragma unroll
                for (int i = 0; i < 12; ++i) {
                    int d = dl + i * 16;
                    float v = latent[latb + (size_t)d * HW + hw0 + ploc];
                    xsf[j * 200 + d] = v;
                    ss = fmaf(v, v, ss);
                }
            }
            part16[j][dl] = ss;
            if (tid < 16) best16[tid] = ~0ull;
            __syncthreads();
            if (tid < 16) {
                float s = 0.f;
                #pragma unroll
                for (int i = 0; i < 16; ++i) s += part16[tid][i];
                inv16[tid] = 1.0f / (sqrtf(s) + 1e-8f);
            }
            __syncthreads();
            // dots: thread owns codewords 4*tid..4*tid+3 for all 16 points
            float4 a[16];
            #pragma unroll
            for (int p = 0; p < 16; ++p) a[p] = make_float4(0.f, 0.f, 0.f, 0.f);
            for (int d = 0; d < DIMS; d += 4) {
                float4 cv0 = ct[(size_t)(d + 0) * 256 + tid];
                float4 cv1 = ct[(size_t)(d + 1) * 256 + tid];
                float4 cv2 = ct[(size_t)(d + 2) * 256 + tid];
                float4 cv3 = ct[(size_t)(d + 3) * 256 + tid];
                #pragma unroll
                for (int p = 0; p < 16; ++p) {
                    float4 xv = *(const float4*)&xsf[p * 200 + d];
                    a[p].x = fmaf(xv.x, cv0.x, a[p].x); a[p].y = fmaf(xv.x, cv0.y, a[p].y);
                    a[p].z = fmaf(xv.x, cv0.z, a[p].z); a[p].w = fmaf(xv.x, cv0.w, a[p].w);
                    a[p].x = fmaf(xv.y, cv1.x, a[p].x); a[p].y = fmaf(xv.y, cv1.y, a[p].y);
                    a[p].z = fmaf(xv.y, cv1.z, a[p].z); a[p].w = fmaf(xv.y, cv1.w, a[p].w);
                    a[p].x = fmaf(xv.z, cv2.x, a[p].x); a[p].y = fmaf(xv.z, cv2.y, a[p].y);
                    a[p].z = fmaf(xv.z, cv2.z, a[p].z); a[p].w = fmaf(xv.z, cv2.w, a[p].w);
                    a[p].x = fmaf(xv.w, cv3.x, a[p].x); a[p].y = fmaf(xv.w, cv3.y, a[p].y);
                    a[p].z = fmaf(xv.w, cv3.z, a[p].z); a[p].w = fmaf(xv.w, cv3.w, a[p].w);
                }
            }
            #pragma unroll
            for (int p = 0; p < 16; ++p) {
                float inv = inv16[p];
                float dot4[4] = {a[p].x, a[p].y, a[p].z, a[p].w};
                unsigned long long loc = ~0ull;
                #pragma unroll
                for (int e = 0; e < 4; ++e) {
                    int k = 4 * tid + e;
                    float dist = c2[k] - 2.f * inv * dot4[e];
                    unsigned ub = __float_as_uint(dist);
                    ub ^= (ub >> 31) ? 0xFFFFFFFFu : 0x80000000u;   // monotonic
                    unsigned long long pk =
                        ((unsigned long long)ub << 32) | (unsigned)k;
                    loc = loc < pk ? loc : pk;
                }
                #pragma unroll
                for (int off = 1; off < 64; off <<= 1) {
                    unsigned long long o = __shfl_xor(loc, off, 64);
                    loc = loc < o ? loc : o;
                }
                if ((tid & 63) == 0) atomicMin(&best16[p], loc);
            }
            __syncthreads();
            if (valid && dl == 0)
                sidx[ploc] = (int)(best16[j] & 0xFFFFFFFFull);
            __syncthreads();
        }
    }

    if (tid < 128) idxf[n0 + tid] = (float)sidx[tid];
    __syncthreads();

    // ---- gather epilogue (q overlays As) ----
    float* q = (float*)As;                      // 32*193*4 = 24.7 KB
    for (int chk = 0; chk < 4; ++chk) {
        int p0 = chk * 32;
        for (int r = wave; r < 32; r += 4) {
            const float* row = cbk + (size_t)sidx[p0 + r] * DIMS;
            for (int c = lane; c < DIMS; c += 64) q[r * 193 + c] = row[c];
        }
        __syncthreads();
        float* ob = out_q + latb + hw0 + p0;
        #pragma unroll
        for (int i = 0; i < 24; ++i) {
            int u = i * 256 + tid;
            int c = u >> 5, p = u & 31;
            ob[(size_t)c * HW + p] = q[p * 193 + c];
        }
        __syncthreads();
    }
}

// ======================= fallback fp32 path (round-1) ====================
__global__ __launch_bounds__(256) void k_norms_fb(const float* __restrict__ latent,
                                                  float* __restrict__ inv_norm) {
    __shared__ float red[256];
    const int tid = threadIdx.x;
    const int n0 = blockIdx.x * 128;
    const int nl = tid & 127;
    const int half = tid >> 7;
    const int b = n0 >> 12;
    const int hw = (n0 & 4095) + nl;
    const float* base = latent + (size_t)b * DIMS * HW + hw;
    float ssq = 0.f;
    for (int c = half; c < DIMS; c += 2) {
        float v = base[(size_t)c * HW];
        ssq = fmaf(v, v, ssq);
    }
    red[tid] = ssq;
    __syncthreads();
    if (half == 0) {
        float s = red[tid] + red[tid + 128];
        inv_norm[n0 + nl] = 1.0f / (sqrtf(s) + 1e-8f);
    }
}

__global__ __launch_bounds__(256) void k_c2_fb(const float* __restrict__ cbk,
                                               float* __restrict__ c2) {
    int k = blockIdx.x * 256 + threadIdx.x;
    if (k >= KCB) return;
    const float4* row = (const float4*)(cbk + (size_t)k * DIMS);
    float s = 0.f;
    #pragma unroll
    for (int i = 0; i < DIMS / 4; ++i) {
        float4 v = row[i];
        s += v.x * v.x + v.y * v.y + v.z * v.z + v.w * v.w;
    }
    c2[k] = s;
}

#define LDX  132
__global__ __launch_bounds__(256) void k_dist_fb(const float* __restrict__ latent,
                                                 const float* __restrict__ cbk,
                                                 const float* __restrict__ inv_norm,
                                                 const float* __restrict__ c2,
                                                 int* __restrict__ idx_out,
                                                 float* __restrict__ idxf_out) {
    __shared__ __align__(16) float xsm[64 * LDX];
    __shared__ __align__(16) float csm[64 * LDX];
    __shared__ unsigned long long red[128];
    const int tid = threadIdx.x;
    const int n0 = blockIdx.x * 128;
    const int b = n0 >> 12;
    const int hw0 = n0 & 4095;
    const int kt = tid & 15;
    const int mt = tid >> 4;
    const float* lat_base = latent + (size_t)b * DIMS * HW + hw0;
    float inv[8];
    #pragma unroll
    for (int i = 0; i < 8; ++i) inv[i] = inv_norm[n0 + mt * 8 + i];
    float best[8];
    int bidx[8];
    #pragma unroll
    for (int i = 0; i < 8; ++i) { best[i] = 3.4e38f; bidx[i] = 0; }
    const int nl = tid & 127;
    const int cp = tid >> 7;
    for (int k0 = 0; k0 < KCB; k0 += 128) {
        float acc[8][8];
        #pragma unroll
        for (int i = 0; i < 8; ++i)
            #pragma unroll
            for (int j = 0; j < 8; ++j) acc[i][j] = 0.f;
        for (int d0 = 0; d0 < DIMS; d0 += 64) {
            __syncthreads();
            for (int cc = cp; cc < 64; cc += 2)
                xsm[cc * LDX + nl] = lat_base[(size_t)(d0 + cc) * HW + nl];
            #pragma unroll
            for (int i = 0; i < 8; ++i) {
                int f4 = tid + 256 * i;
                int kk = f4 >> 4;
                int dq = f4 & 15;
                float4 v = *(const float4*)(cbk + (size_t)(k0 + kk) * DIMS + d0 + dq * 4);
                csm[(dq * 4 + 0) * LDX + kk] = v.x;
                csm[(dq * 4 + 1) * LDX + kk] = v.y;
                csm[(dq * 4 + 2) * LDX + kk] = v.z;
                csm[(dq * 4 + 3) * LDX + kk] = v.w;
            }
            __syncthreads();
            for (int d = 0; d < 64; ++d) {
                const float* xr = &xsm[d * LDX + mt * 8];
                const float* cr = &csm[d * LDX + kt * 8];
                float x8[8], c8[8];
                *(float4*)&x8[0] = *(const float4*)&xr[0];
                *(float4*)&x8[4] = *(const float4*)&xr[4];
                *(float4*)&c8[0] = *(const float4*)&cr[0];
                *(float4*)&c8[4] = *(const float4*)&cr[4];
                #pragma unroll
                for (int i = 0; i < 8; ++i)
                    #pragma unroll
                    for (int j = 0; j < 8; ++j)
                        acc[i][j] = fmaf(x8[i], c8[j], acc[i][j]);
            }
        }
        float cc2[8];
        #pragma unroll
        for (int j = 0; j < 8; ++j) cc2[j] = c2[k0 + kt * 8 + j];
        #pragma unroll
        for (int i = 0; i < 8; ++i)
            #pragma unroll
            for (int j = 0; j < 8; ++j) {
                float t = inv[i] * acc[i][j];
                float dist = fmaf(-2.f, t, cc2[j]);
                int kidx = k0 + kt * 8 + j;
                if (dist < best[i]) { best[i] = dist; bidx[i] = kidx; }
            }
    }
    if (tid < 128) red[tid] = ~0ull;
    __syncthreads();
    #pragma unroll
    for (int i = 0; i < 8; ++i) {
        unsigned long long p =
            ((unsigned long long)__float_as_uint(best[i]) << 32) | (unsigned)bidx[i];
        atomicMin(&red[mt * 8 + i], p);
    }
    __syncthreads();
    if (tid < 128) {
        int k = (int)(red[tid] & 0xFFFFFFFFu);
        idx_out[n0 + tid] = k;
        idxf_out[n0 + tid] = (float)k;
    }
}

__global__ __launch_bounds__(256) void k_gather(const float* __restrict__ cbk,
                                                const int* __restrict__ idx,
                                                float* __restrict__ out) {
    __shared__ float q[64 * 193];
    __shared__ int sidx[64];
    const int tid = threadIdx.x;
    const int n0 = blockIdx.x * 64;
    const int b = n0 >> 12;
    const int hw0 = n0 & 4095;
    const int lane = tid & 63;
    const int grp = tid >> 6;

    if (tid < 64) sidx[tid] = idx[n0 + tid];
    __syncthreads();
    for (int r = grp; r < 64; r += 4) {
        const float* row = cbk + (size_t)sidx[r] * DIMS;
        for (int c = lane; c < DIMS; c += 64) q[r * 193 + c] = row[c];
    }
    __syncthreads();
    float* obase = out + (size_t)b * DIMS * HW + hw0;
    for (int c = grp; c < DIMS; c += 4) {
        obase[(size_t)c * HW + lane] = q[lane * 193 + c];
    }
}

// ================================ launch ================================
extern "C" void kernel_launch(void* const* d_in, const int* in_sizes, int n_in,
                              void* d_out, int out_size, void* d_ws, size_t ws_size,
                              hipStream_t stream) {
    const float* latent = (const float*)d_in[0];
    const float* cbk = (const float*)d_in[1];
    float* out = (float*)d_out;
    float* out_q = out;
    float* out_idx = out + QELEMS;

    if (ws_size >= 2u * 1024u * 1024u) {
        // ws layout (bytes):
        char* w = (char*)d_ws;
        _Float16* Bpf = (_Float16*)w;                          //    393,216
        float* cbkT = (float*)(w + 393216);                    //    786,432
        float* c2 = (float*)(w + 1179648);                     //      4,096

        k_prep<<<KCB / 64, 256, 0, stream>>>(cbk, Bpf, cbkT, c2);
        k_gemm_f<<<512, 256, 0, stream>>>(latent, Bpf, cbkT, c2, cbk,
                                          out_q, out_idx);
    } else {
        float* inv_norm = (float*)d_ws;
        float* c2 = inv_norm + NPTS;
        int* idx = (int*)(c2 + KCB);
        k_norms_fb<<<NPTS / 128, 256, 0, stream>>>(latent, inv_norm);
        k_c2_fb<<<4, 256, 0, stream>>>(cbk, c2);
        k_dist_fb<<<NPTS / 128, 256, 0, stream>>>(latent, cbk, inv_norm, c2, idx, out_idx);
        k_gather<<<NPTS / 64, 256, 0, stream>>>(cbk, idx, out_q);
    }
}

// Round 6
// 216.529 us; speedup vs baseline: 1.4171x; 1.1265x over previous
//
#include <hip/hip_runtime.h>

// Problem: latent (16,192,64,64) fp32, codebook (1024,192) fp32.
// N = 65536 points, D = 192, K = 1024.
// d_out = [quantized: 12582912 fp32][indices-as-float: 65536].

#define NPTS   65536
#define DIMS   192
#define KCB    1024
#define HW     4096
#define QELEMS 12582912

typedef __attribute__((ext_vector_type(8))) _Float16 f16x8;
typedef __attribute__((ext_vector_type(4))) _Float16 f16x4;
typedef __attribute__((ext_vector_type(4))) float f32x4;

// ============================ f16 MFMA path =============================
// Codebook rows are unit-normalized -> argmin dist == argmax dot; inv_norm>0
// per point -> rank RAW dots. q = trunc(fma(dot_raw, 2^16, 2^21)). f16 dot
// error <= 64*||x||+1 q-units, so with Mq = 152*||x||+4:
//  - if q1-q3 >= Mq: true winner is in {k1,k2}; resolve with exact fp32
//    2-candidate compare (arithmetic identical to the proven full rescore).
//  - if q1-q3 <  Mq: full exact 1024-codeword rescore (rare, ~0.6%).
// Top-3 tracked branchlessly; rescore formulas replicate rounds 0-5's
// passing arithmetic bit-for-bit per point.

__device__ __forceinline__ void async_load16(const void* g, void* l) {
    __builtin_amdgcn_global_load_lds(
        (const __attribute__((address_space(1))) unsigned int*)g,
        (__attribute__((address_space(3))) unsigned int*)l, 16, 0, 0);
}

// branchless insert of p into sorted top-3 (b >= s >= t)
__device__ __forceinline__ void top3_ins(unsigned& b, unsigned& s, unsigned& t,
                                         unsigned p) {
    unsigned m1 = min(b, p);
    unsigned m2 = min(s, p);
    b = max(b, p);
    s = max(s, m1);
    t = max(t, m2);
}

// ---- fused prep: cbk -> {Bpf f16 group-major [g][k][64], cbkT, c2} ----
__global__ __launch_bounds__(256) void k_prep(const float* __restrict__ cbk,
                                              _Float16* __restrict__ Bpf,
                                              float* __restrict__ cbkT,
                                              float* __restrict__ c2) {
    __shared__ float q[64 * 193];
    const int tid = threadIdx.x;
    const int k0 = blockIdx.x * 64;
    const int lane = tid & 63;
    const int grp = tid >> 6;
    for (int r = grp; r < 64; r += 4) {
        const float* row = cbk + (size_t)(k0 + r) * DIMS;
        for (int c = lane; c < DIMS; c += 64) q[r * 193 + c] = row[c];
    }
    __syncthreads();
    for (int d = grp; d < DIMS; d += 4)
        cbkT[(size_t)d * KCB + k0 + lane] = q[lane * 193 + d];
    for (int r = grp; r < 64; r += 4)
        for (int c = lane; c < DIMS; c += 64)
            Bpf[((size_t)(c >> 6) * KCB + k0 + r) * 64 + (c & 63)] =
                (_Float16)q[r * 193 + c];
    if (tid < 64) {
        float s = 0.f;
        #pragma unroll 4
        for (int c = 0; c < DIMS; ++c) {
            float v = q[tid * 193 + c];
            s = fmaf(v, v, s);
        }
        c2[k0 + tid] = s;
    }
}

// ---- fused: latent->f16 LDS slab + MFMA GEMM + top-3 argmax + cheap exact
//      resolution + gather ----
__global__ __launch_bounds__(256, 2) void k_gemm_f(const float* __restrict__ latent,
                                                   const _Float16* __restrict__ Bpf,
                                                   const float* __restrict__ cbkT,
                                                   const float* __restrict__ c2,
                                                   const float* __restrict__ cbk,
                                                   float* __restrict__ out_q,
                                                   float* __restrict__ idxf) {
    __shared__ __align__(16) _Float16 As[128 * 200];   // 51200 B (xs/gather overlay)
    __shared__ __align__(16) _Float16 Bs[128 * 64];    // 16384 B
    __shared__ float nrm_s[128];
    __shared__ uint4 t2buf[256];
    __shared__ int sidx[128];
    __shared__ int slist_pair[128];
    __shared__ int slist_full[128];
    __shared__ int scnt_pair, scnt_full;
    __shared__ float part16[16][16];
    __shared__ float inv16[16];
    __shared__ unsigned long long best16[16];

    const int tid = threadIdx.x;
    const int wave = tid >> 6;
    const int lane = tid & 63;
    const int quad = lane >> 4;
    const int l15 = lane & 15;
    const int wm = (wave >> 1) * 64;
    const int wn = (wave & 1) * 64;
    const int n0 = blockIdx.x * 128;
    const int bB = n0 >> 12;
    const int hw0 = n0 & 4095;
    const size_t latb = (size_t)bB * DIMS * HW;

    // ---- phase 0: load raw latent slab once, f16-convert, ssq ----
    {
        float* part = (float*)Bs;               // overlay (pre-K-loop)
        const float* lat = latent + latb + hw0;
        const int p = tid & 127, ch = tid >> 7;
        float ss = 0.f;
        #pragma unroll 4
        for (int i = 0; i < 24; ++i) {
            int c0 = i * 8 + ch * 4;
            float v0 = lat[(size_t)(c0 + 0) * HW + p];
            float v1 = lat[(size_t)(c0 + 1) * HW + p];
            float v2 = lat[(size_t)(c0 + 2) * HW + p];
            float v3 = lat[(size_t)(c0 + 3) * HW + p];
            ss = fmaf(v0, v0, fmaf(v1, v1, fmaf(v2, v2, fmaf(v3, v3, ss))));
            f16x4 h = { (_Float16)v0, (_Float16)v1, (_Float16)v2, (_Float16)v3 };
            *(f16x4*)&As[p * 200 + c0] = h;
        }
        part[ch * 128 + p] = ss;
        __syncthreads();
        if (tid < 128)
            nrm_s[tid] = sqrtf(part[tid] + part[128 + tid]);
        if (tid == 0) { scnt_pair = 0; scnt_full = 0; }
        __syncthreads();                        // part consumed before Bs reuse
    }

    unsigned rb[16], rs[16], rt[16];
    #pragma unroll
    for (int i = 0; i < 16; ++i) { rb[i] = 0u; rs[i] = 0u; rt[i] = 0u; }

    // ---- K-loop: nb (8 codeword strips) x g (3 dim groups) ----
    for (int nb = 0; nb < 8; ++nb) {
        f32x4 acc[4][4];
        #pragma unroll
        for (int mt = 0; mt < 4; ++mt)
            #pragma unroll
            for (int nt = 0; nt < 4; ++nt)
                #pragma unroll
                for (int r = 0; r < 4; ++r) acc[mt][nt][r] = 0.f;

        for (int g = 0; g < 3; ++g) {
            __syncthreads();
            #pragma unroll
            for (int i = 0; i < 4; ++i) {
                int u = i * 256 + tid;          // 1024 16B-units
                int m = u >> 3, c = u & 7;
                int sw = c ^ (m & 7);           // XOR swizzle
                async_load16(Bpf + (((size_t)g * KCB + nb * 128 + m) * 8 + sw) * 8,
                             &Bs[u * 8]);
            }
            asm volatile("s_waitcnt vmcnt(0)" ::: "memory");
            __syncthreads();
            #pragma unroll
            for (int s = 0; s < 2; ++s) {
                f16x8 af[4], bfr[4];
                #pragma unroll
                for (int mt = 0; mt < 4; ++mt) {
                    int m = wm + mt * 16 + l15;
                    af[mt] = *(const f16x8*)&As[m * 200 + g * 64 + s * 32 + quad * 8];
                }
                #pragma unroll
                for (int nt = 0; nt < 4; ++nt) {
                    int n = wn + nt * 16 + l15;
                    int c = (s * 4 + quad) ^ (n & 7);
                    bfr[nt] = *(const f16x8*)&Bs[n * 64 + c * 8];
                }
                #pragma unroll
                for (int mt = 0; mt < 4; ++mt)
                    #pragma unroll
                    for (int nt = 0; nt < 4; ++nt)
                        acc[mt][nt] = __builtin_amdgcn_mfma_f32_16x16x32_f16(
                            af[mt], bfr[nt], acc[mt][nt], 0, 0, 0);
            }
        }

        // per-nb epilogue: quantize RAW dots; insert into top-3
        int kbase = nb * 128 + wn;
        #pragma unroll
        for (int mt = 0; mt < 4; ++mt) {
            #pragma unroll
            for (int r = 0; r < 4; ++r) {
                const int i = mt * 4 + r;
                #pragma unroll
                for (int nt = 0; nt < 4; ++nt) {
                    unsigned pv = ((unsigned)fmaf(acc[mt][nt][r], 65536.f, 2097152.f) << 10)
                                  | (unsigned)(kbase + nt * 16 + l15);
                    top3_ins(rb[i], rs[i], rt[i], pv);
                }
            }
        }
    }

    // ---- cross-lane / cross-wave top-3 merge ----
    __syncthreads();
    #pragma unroll
    for (int i = 0; i < 16; ++i) {
        unsigned b = rb[i], s = rs[i], t = rt[i];
        #pragma unroll
        for (int off = 1; off < 16; off <<= 1) {
            unsigned ob = __shfl_xor(b, off, 64);
            unsigned os = __shfl_xor(s, off, 64);
            unsigned ot = __shfl_xor(t, off, 64);
            top3_ins(b, s, t, ob);
            top3_ins(b, s, t, os);
            top3_ins(b, s, t, ot);
        }
        if (l15 == 0) {
            int mt = i >> 2, r = i & 3;
            int mloc = wm + mt * 16 + quad * 4 + r;
            t2buf[mloc * 2 + (wave & 1)] = make_uint4(b, s, t, 0u);
        }
    }
    __syncthreads();
    if (tid < 128) {
        uint4 x = t2buf[tid * 2];
        uint4 y = t2buf[tid * 2 + 1];
        unsigned b = x.x, s = x.y, t = x.z;
        top3_ins(b, s, t, y.x);
        top3_ins(b, s, t, y.y);
        top3_ins(b, s, t, y.z);
        sidx[tid] = (int)(b & 1023u);
        unsigned q1 = b >> 10, q2 = s >> 10, q3 = t >> 10;
        unsigned Mq = (unsigned)fmaf(152.0f, nrm_s[tid], 4.0f);
        if (q1 - q3 < Mq) {                     // >=2 rivals in window: full
            int pos = atomicAdd(&scnt_full, 1);
            slist_full[pos] = tid;
        } else if (q1 - q2 < Mq) {              // winner provably in {k1,k2}
            int pos = atomicAdd(&scnt_pair, 1);
            slist_pair[pos] = tid | ((int)(b & 1023u) << 7)
                                  | ((int)(s & 1023u) << 17);
        }
    }
    __syncthreads();
    const int nfull = scnt_full;
    const int npair = scnt_pair;

    // ---- full exact fp32 rescore (rare; identical arithmetic to r0-r5) ----
    {
        float* xsf = (float*)As;                // xs[16][200] overlay
        const float4* ct = (const float4*)cbkT; // [d][256] float4
        const int j = tid >> 4, dl = tid & 15;
        for (int base = 0; base < nfull; base += 16) {
            const bool valid = (base + j) < nfull;
            const int ploc = valid ? slist_full[base + j] : 0;
            float ss = 0.f;
            if (valid) {
                #pragma unroll
                for (int i = 0; i < 12; ++i) {
                    int d = dl + i * 16;
                    float v = latent[latb + (size_t)d * HW + hw0 + ploc];
                    xsf[j * 200 + d] = v;
                    ss = fmaf(v, v, ss);
                }
            }
            part16[j][dl] = ss;
            if (tid < 16) best16[tid] = ~0ull;
            __syncthreads();
            if (tid < 16) {
                float s = 0.f;
                #pragma unroll
                for (int i = 0; i < 16; ++i) s += part16[tid][i];
                inv16[tid] = 1.0f / (sqrtf(s) + 1e-8f);
            }
            __syncthreads();
            float4 a[16];
            #pragma unroll
            for (int p = 0; p < 16; ++p) a[p] = make_float4(0.f, 0.f, 0.f, 0.f);
            for (int d = 0; d < DIMS; d += 4) {
                float4 cv0 = ct[(size_t)(d + 0) * 256 + tid];
                float4 cv1 = ct[(size_t)(d + 1) * 256 + tid];
                float4 cv2 = ct[(size_t)(d + 2) * 256 + tid];
                float4 cv3 = ct[(size_t)(d + 3) * 256 + tid];
                #pragma unroll
                for (int p = 0; p < 16; ++p) {
                    float4 xv = *(const float4*)&xsf[p * 200 + d];
                    a[p].x = fmaf(xv.x, cv0.x, a[p].x); a[p].y = fmaf(xv.x, cv0.y, a[p].y);
                    a[p].z = fmaf(xv.x, cv0.z, a[p].z); a[p].w = fmaf(xv.x, cv0.w, a[p].w);
                    a[p].x = fmaf(xv.y, cv1.x, a[p].x); a[p].y = fmaf(xv.y, cv1.y, a[p].y);
                    a[p].z = fmaf(xv.y, cv1.z, a[p].z); a[p].w = fmaf(xv.y, cv1.w, a[p].w);
                    a[p].x = fmaf(xv.z, cv2.x, a[p].x); a[p].y = fmaf(xv.z, cv2.y, a[p].y);
                    a[p].z = fmaf(xv.z, cv2.z, a[p].z); a[p].w = fmaf(xv.z, cv2.w, a[p].w);
                    a[p].x = fmaf(xv.w, cv3.x, a[p].x); a[p].y = fmaf(xv.w, cv3.y, a[p].y);
                    a[p].z = fmaf(xv.w, cv3.z, a[p].z); a[p].w = fmaf(xv.w, cv3.w, a[p].w);
                }
            }
            #pragma unroll
            for (int p = 0; p < 16; ++p) {
                float inv = inv16[p];
                float dot4[4] = {a[p].x, a[p].y, a[p].z, a[p].w};
                unsigned long long loc = ~0ull;
                #pragma unroll
                for (int e = 0; e < 4; ++e) {
                    int k = 4 * tid + e;
                    float dist = c2[k] - 2.f * inv * dot4[e];
                    unsigned ub = __float_as_uint(dist);
                    ub ^= (ub >> 31) ? 0xFFFFFFFFu : 0x80000000u;   // monotonic
                    unsigned long long pk =
                        ((unsigned long long)ub << 32) | (unsigned)k;
                    loc = loc < pk ? loc : pk;
                }
                #pragma unroll
                for (int off = 1; off < 64; off <<= 1) {
                    unsigned long long o = __shfl_xor(loc, off, 64);
                    loc = loc < o ? loc : o;
                }
                if ((tid & 63) == 0) atomicMin(&best16[p], loc);
            }
            __syncthreads();
            if (valid && dl == 0)
                sidx[ploc] = (int)(best16[j] & 0xFFFFFFFFull);
            __syncthreads();
        }
    }

    // ---- pair resolution: one thread per flagged pair, exact fp32, same
    //      per-point arithmetic (ss partials, fma chain order, dist expr) ----
    for (int i = tid; i < npair; i += 256) {
        int pk = slist_pair[i];
        int ploc = pk & 127;
        int k1 = (pk >> 7) & 1023;
        int k2 = (pk >> 17) & 1023;
        const float* xr = latent + latb + hw0 + ploc;
        const float* c1 = cbk + (size_t)k1 * DIMS;
        const float* c2r = cbk + (size_t)k2 * DIMS;
        float a1 = 0.f, a2 = 0.f;
        float pp[16];
        #pragma unroll
        for (int e = 0; e < 16; ++e) pp[e] = 0.f;
        for (int d0 = 0; d0 < DIMS; d0 += 16) {
            #pragma unroll
            for (int e = 0; e < 16; ++e) {
                int d = d0 + e;
                float xv = xr[(size_t)d * HW];
                a1 = fmaf(xv, c1[d], a1);
                a2 = fmaf(xv, c2r[d], a2);
                pp[e] = fmaf(xv, xv, pp[e]);
            }
        }
        float ss = 0.f;
        #pragma unroll
        for (int e = 0; e < 16; ++e) ss += pp[e];
        float inv = 1.0f / (sqrtf(ss) + 1e-8f);
        float d1 = c2[k1] - 2.f * inv * a1;
        float d2 = c2[k2] - 2.f * inv * a2;
        unsigned u1 = __float_as_uint(d1);
        u1 ^= (u1 >> 31) ? 0xFFFFFFFFu : 0x80000000u;
        unsigned u2 = __float_as_uint(d2);
        u2 ^= (u2 >> 31) ? 0xFFFFFFFFu : 0x80000000u;
        unsigned long long p1 = ((unsigned long long)u1 << 32) | (unsigned)k1;
        unsigned long long p2 = ((unsigned long long)u2 << 32) | (unsigned)k2;
        sidx[ploc] = (int)((p1 < p2 ? p1 : p2) & 1023ull);
    }
    __syncthreads();

    if (tid < 128) idxf[n0 + tid] = (float)sidx[tid];
    __syncthreads();

    // ---- gather epilogue (q overlays As) ----
    float* q = (float*)As;                      // 32*193*4 = 24.7 KB
    for (int chk = 0; chk < 4; ++chk) {
        int p0 = chk * 32;
        for (int r = wave; r < 32; r += 4) {
            const float* row = cbk + (size_t)sidx[p0 + r] * DIMS;
            for (int c = lane; c < DIMS; c += 64) q[r * 193 + c] = row[c];
        }
        __syncthreads();
        float* ob = out_q + latb + hw0 + p0;
        #pragma unroll
        for (int i = 0; i < 24; ++i) {
            int u = i * 256 + tid;
            int c = u >> 5, p = u & 31;
            ob[(size_t)c * HW + p] = q[p * 193 + c];
        }
        __syncthreads();
    }
}

// ======================= fallback fp32 path (round-1) ====================
__global__ __launch_bounds__(256) void k_norms_fb(const float* __restrict__ latent,
                                                  float* __restrict__ inv_norm) {
    __shared__ float red[256];
    const int tid = threadIdx.x;
    const int n0 = blockIdx.x * 128;
    const int nl = tid & 127;
    const int half = tid >> 7;
    const int b = n0 >> 12;
    const int hw = (n0 & 4095) + nl;
    const float* base = latent + (size_t)b * DIMS * HW + hw;
    float ssq = 0.f;
    for (int c = half; c < DIMS; c += 2) {
        float v = base[(size_t)c * HW];
        ssq = fmaf(v, v, ssq);
    }
    red[tid] = ssq;
    __syncthreads();
    if (half == 0) {
        float s = red[tid] + red[tid + 128];
        inv_norm[n0 + nl] = 1.0f / (sqrtf(s) + 1e-8f);
    }
}

__global__ __launch_bounds__(256) void k_c2_fb(const float* __restrict__ cbk,
                                               float* __restrict__ c2) {
    int k = blockIdx.x * 256 + threadIdx.x;
    if (k >= KCB) return;
    const float4* row = (const float4*)(cbk + (size_t)k * DIMS);
    float s = 0.f;
    #pragma unroll
    for (int i = 0; i < DIMS / 4; ++i) {
        float4 v = row[i];
        s += v.x * v.x + v.y * v.y + v.z * v.z + v.w * v.w;
    }
    c2[k] = s;
}

#define LDX  132
__global__ __launch_bounds__(256) void k_dist_fb(const float* __restrict__ latent,
                                                 const float* __restrict__ cbk,
                                                 const float* __restrict__ inv_norm,
                                                 const float* __restrict__ c2,
                                                 int* __restrict__ idx_out,
                                                 float* __restrict__ idxf_out) {
    __shared__ __align__(16) float xsm[64 * LDX];
    __shared__ __align__(16) float csm[64 * LDX];
    __shared__ unsigned long long red[128];
    const int tid = threadIdx.x;
    const int n0 = blockIdx.x * 128;
    const int b = n0 >> 12;
    const int hw0 = n0 & 4095;
    const int kt = tid & 15;
    const int mt = tid >> 4;
    const float* lat_base = latent + (size_t)b * DIMS * HW + hw0;
    float inv[8];
    #pragma unroll
    for (int i = 0; i < 8; ++i) inv[i] = inv_norm[n0 + mt * 8 + i];
    float best[8];
    int bidx[8];
    #pragma unroll
    for (int i = 0; i < 8; ++i) { best[i] = 3.4e38f; bidx[i] = 0; }
    const int nl = tid & 127;
    const int cp = tid >> 7;
    for (int k0 = 0; k0 < KCB; k0 += 128) {
        float acc[8][8];
        #pragma unroll
        for (int i = 0; i < 8; ++i)
            #pragma unroll
            for (int j = 0; j < 8; ++j) acc[i][j] = 0.f;
        for (int d0 = 0; d0 < DIMS; d0 += 64) {
            __syncthreads();
            for (int cc = cp; cc < 64; cc += 2)
                xsm[cc * LDX + nl] = lat_base[(size_t)(d0 + cc) * HW + nl];
            #pragma unroll
            for (int i = 0; i < 8; ++i) {
                int f4 = tid + 256 * i;
                int kk = f4 >> 4;
                int dq = f4 & 15;
                float4 v = *(const float4*)(cbk + (size_t)(k0 + kk) * DIMS + d0 + dq * 4);
                csm[(dq * 4 + 0) * LDX + kk] = v.x;
                csm[(dq * 4 + 1) * LDX + kk] = v.y;
                csm[(dq * 4 + 2) * LDX + kk] = v.z;
                csm[(dq * 4 + 3) * LDX + kk] = v.w;
            }
            __syncthreads();
            for (int d = 0; d < 64; ++d) {
                const float* xr = &xsm[d * LDX + mt * 8];
                const float* cr = &csm[d * LDX + kt * 8];
                float x8[8], c8[8];
                *(float4*)&x8[0] = *(const float4*)&xr[0];
                *(float4*)&x8[4] = *(const float4*)&xr[4];
                *(float4*)&c8[0] = *(const float4*)&cr[0];
                *(float4*)&c8[4] = *(const float4*)&cr[4];
                #pragma unroll
                for (int i = 0; i < 8; ++i)
                    #pragma unroll
                    for (int j = 0; j < 8; ++j)
                        acc[i][j] = fmaf(x8[i], c8[j], acc[i][j]);
            }
        }
        float cc2[8];
        #pragma unroll
        for (int j = 0; j < 8; ++j) cc2[j] = c2[k0 + kt * 8 + j];
        #pragma unroll
        for (int i = 0; i < 8; ++i)
            #pragma unroll
            for (int j = 0; j < 8; ++j) {
                float t = inv[i] * acc[i][j];
                float dist = fmaf(-2.f, t, cc2[j]);
                int kidx = k0 + kt * 8 + j;
                if (dist < best[i]) { best[i] = dist; bidx[i] = kidx; }
            }
    }
    if (tid < 128) red[tid] = ~0ull;
    __syncthreads();
    #pragma unroll
    for (int i = 0; i < 8; ++i) {
        unsigned long long p =
            ((unsigned long long)__float_as_uint(best[i]) << 32) | (unsigned)bidx[i];
        atomicMin(&red[mt * 8 + i], p);
    }
    __syncthreads();
    if (tid < 128) {
        int k = (int)(red[tid] & 0xFFFFFFFFu);
        idx_out[n0 + tid] = k;
        idxf_out[n0 + tid] = (float)k;
    }
}

__global__ __launch_bounds__(256) void k_gather(const float* __restrict__ cbk,
                                                const int* __restrict__ idx,
                                                float* __restrict__ out) {
    __shared__ float q[64 * 193];
    __shared__ int sidx[64];
    const int tid = threadIdx.x;
    const int n0 = blockIdx.x * 64;
    const int b = n0 >> 12;
    const int hw0 = n0 & 4095;
    const int lane = tid & 63;
    const int grp = tid >> 6;

    if (tid < 64) sidx[tid] = idx[n0 + tid];
    __syncthreads();
    for (int r = grp; r < 64; r += 4) {
        const float* row = cbk + (size_t)sidx[r] * DIMS;
        for (int c = lane; c < DIMS; c += 64) q[r * 193 + c] = row[c];
    }
    __syncthreads();
    float* obase = out + (size_t)b * DIMS * HW + hw0;
    for (int c = grp; c < DIMS; c += 4) {
        obase[(size_t)c * HW + lane] = q[lane * 193 + c];
    }
}

// ================================ launch ================================
extern "C" void kernel_launch(void* const* d_in, const int* in_sizes, int n_in,
                              void* d_out, int out_size, void* d_ws, size_t ws_size,
                              hipStream_t stream) {
    const float* latent = (const float*)d_in[0];
    const float* cbk = (const float*)d_in[1];
    float* out = (float*)d_out;
    float* out_q = out;
    float* out_idx = out + QELEMS;

    if (ws_size >= 2u * 1024u * 1024u) {
        // ws layout (bytes):
        char* w = (char*)d_ws;
        _Float16* Bpf = (_Float16*)w;                          //    393,216
        float* cbkT = (float*)(w + 393216);                    //    786,432
        float* c2 = (float*)(w + 1179648);                     //      4,096

        k_prep<<<KCB / 64, 256, 0, stream>>>(cbk, Bpf, cbkT, c2);
        k_gemm_f<<<512, 256, 0, stream>>>(latent, Bpf, cbkT, c2, cbk,
                                          out_q, out_idx);
    } else {
        float* inv_norm = (float*)d_ws;
        float* c2 = inv_norm + NPTS;
        int* idx = (int*)(c2 + KCB);
        k_norms_fb<<<NPTS / 128, 256, 0, stream>>>(latent, inv_norm);
        k_c2_fb<<<4, 256, 0, stream>>>(cbk, c2);
        k_dist_fb<<<NPTS / 128, 256, 0, stream>>>(latent, cbk, inv_norm, c2, idx, out_idx);
        k_gather<<<NPTS / 64, 256, 0, stream>>>(cbk, idx, out_q);
    }
}

// Round 7
// 194.937 us; speedup vs baseline: 1.5740x; 1.1108x over previous
//
#include <hip/hip_runtime.h>

// Problem: latent (16,192,64,64) fp32, codebook (1024,192) fp32.
// N = 65536 points, D = 192, K = 1024.
// d_out = [quantized: 12582912 fp32][indices-as-float: 65536].

#define NPTS   65536
#define DIMS   192
#define KCB    1024
#define HW     4096
#define QELEMS 12582912

typedef __attribute__((ext_vector_type(8))) _Float16 f16x8;
typedef __attribute__((ext_vector_type(4))) _Float16 f16x4;
typedef __attribute__((ext_vector_type(4))) float f32x4;

// ============================ f16 MFMA path =============================
// Codebook rows are unit-normalized -> argmin dist == argmax dot; inv_norm>0
// per point -> rank RAW dots. q = trunc(fma(dot_raw, 2^16, 2^21)). f16 dot
// error <= 64*||x||+1 q-units, so with Mq = 152*||x||+4:
//  - if q1-q3 >= Mq: true winner is in {k1,k2}; resolve with exact fp32
//    2-candidate compare (arithmetic identical to the proven full rescore).
//  - if q1-q3 <  Mq: full exact 1024-codeword rescore (rare, ~1.3%).
// K-loop: 48 phases of 8KB subtiles (128k x 32d), double-buffered within a
// single 16KB footprint; stage(ph+1) issued before compute(ph) so HBM/L2
// latency hides under MFMA + the per-strip top-3 epilogue. vmcnt(0)-only
// discipline (counted vmcnt proved fragile in round 2).

__device__ __forceinline__ void async_load16(const void* g, void* l) {
    __builtin_amdgcn_global_load_lds(
        (const __attribute__((address_space(1))) unsigned int*)g,
        (__attribute__((address_space(3))) unsigned int*)l, 16, 0, 0);
}

// branchless insert of p into sorted top-3 (b >= s >= t)
__device__ __forceinline__ void top3_ins(unsigned& b, unsigned& s, unsigned& t,
                                         unsigned p) {
    unsigned m1 = min(b, p);
    unsigned m2 = min(s, p);
    b = max(b, p);
    s = max(s, m1);
    t = max(t, m2);
}

// ---- fused prep: cbk -> {Bpf f16 group-major [g][k][64], cbkT, c2} ----
// grid 64 x 256; block handles 16 codewords staged once in LDS.
__global__ __launch_bounds__(256) void k_prep(const float* __restrict__ cbk,
                                              _Float16* __restrict__ Bpf,
                                              float* __restrict__ cbkT,
                                              float* __restrict__ c2) {
    __shared__ float q[16 * 193];
    const int tid = threadIdx.x;
    const int k0 = blockIdx.x * 16;
    const int lane = tid & 63;
    const int grp = tid >> 6;
    for (int r = grp; r < 16; r += 4) {
        const float* row = cbk + (size_t)(k0 + r) * DIMS;
        for (int c = lane; c < DIMS; c += 64) q[r * 193 + c] = row[c];
    }
    __syncthreads();
    // fp32 transpose for rescore: 16 lanes of k per dim group
    {
        const int kl = tid & 15, dg = tid >> 4;
        for (int d = dg; d < DIMS; d += 16)
            cbkT[(size_t)d * KCB + k0 + kl] = q[kl * 193 + d];
    }
    // f16 group-major [g][k][64]
    for (int r = grp; r < 16; r += 4)
        for (int c = lane; c < DIMS; c += 64)
            Bpf[((size_t)(c >> 6) * KCB + k0 + r) * 64 + (c & 63)] =
                (_Float16)q[r * 193 + c];
    // row squared norms
    if (tid < 16) {
        float s = 0.f;
        #pragma unroll 4
        for (int c = 0; c < DIMS; ++c) {
            float v = q[tid * 193 + c];
            s = fmaf(v, v, s);
        }
        c2[k0 + tid] = s;
    }
}

// ---- fused: latent->f16 LDS slab + dbuf-subtile MFMA + top-3 argmax +
//      cheap exact resolution + gather ----
__global__ __launch_bounds__(256, 2) void k_gemm_f(const float* __restrict__ latent,
                                                   const _Float16* __restrict__ Bpf,
                                                   const float* __restrict__ cbkT,
                                                   const float* __restrict__ c2,
                                                   const float* __restrict__ cbk,
                                                   float* __restrict__ out_q,
                                                   float* __restrict__ idxf) {
    __shared__ __align__(16) _Float16 As[128 * 200];   // 51200 B (xs/gather overlay)
    __shared__ __align__(16) _Float16 Bs[2][4096];     // 2 x 8192 B dbuf
    __shared__ float nrm_s[128];
    __shared__ uint4 t2buf[256];
    __shared__ int sidx[128];
    __shared__ int slist_pair[128];
    __shared__ int slist_full[128];
    __shared__ int scnt_pair, scnt_full;
    __shared__ float part8[8][32];
    __shared__ float inv8[8];
    __shared__ unsigned long long best8[8];

    const int tid = threadIdx.x;
    const int wave = tid >> 6;
    const int lane = tid & 63;
    const int quad = lane >> 4;
    const int l15 = lane & 15;
    const int wm = (wave >> 1) * 64;
    const int wn = (wave & 1) * 64;
    const int n0 = blockIdx.x * 128;
    const int bB = n0 >> 12;
    const int hw0 = n0 & 4095;
    const size_t latb = (size_t)bB * DIMS * HW;

    // ---- phase 0: load raw latent slab once, f16-convert, ssq ----
    {
        float* part = (float*)&Bs[0][0];        // overlay (pre-K-loop)
        const float* lat = latent + latb + hw0;
        const int p = tid & 127, ch = tid >> 7;
        float ss = 0.f;
        #pragma unroll 4
        for (int i = 0; i < 24; ++i) {
            int c0 = i * 8 + ch * 4;
            float v0 = lat[(size_t)(c0 + 0) * HW + p];
            float v1 = lat[(size_t)(c0 + 1) * HW + p];
            float v2 = lat[(size_t)(c0 + 2) * HW + p];
            float v3 = lat[(size_t)(c0 + 3) * HW + p];
            ss = fmaf(v0, v0, fmaf(v1, v1, fmaf(v2, v2, fmaf(v3, v3, ss))));
            f16x4 h = { (_Float16)v0, (_Float16)v1, (_Float16)v2, (_Float16)v3 };
            *(f16x4*)&As[p * 200 + c0] = h;
        }
        part[ch * 128 + p] = ss;
        __syncthreads();
        if (tid < 128)
            nrm_s[tid] = sqrtf(part[tid] + part[128 + tid]);
        if (tid == 0) { scnt_pair = 0; scnt_full = 0; }
        __syncthreads();                        // part consumed before Bs reuse
    }

    // staging constants: thread stages 16B-units {tid, tid+256} of 512.
    // Subtile = 128 k x 32 dims; unit u -> (k=u>>2, j_phys=u&3);
    // swizzle j_src = j_phys ^ ((k>>1)&3)  => b128 reads are 2-way (free).
    const int sk0 = tid >> 2,        sj0 = (tid & 3) ^ ((sk0 >> 1) & 3);
    const int sk1 = (tid + 256) >> 2, sj1 = ((tid + 256) & 3) ^ ((sk1 >> 1) & 3);

    // prologue: stage phase 0 (nb=0, g=0, s=0) into Bs[0]
    async_load16(Bpf + ((size_t)sk0) * 64 + sj0 * 8, &Bs[0][tid * 8]);
    async_load16(Bpf + ((size_t)sk1) * 64 + sj1 * 8, &Bs[0][(tid + 256) * 8]);

    unsigned rb[16], rs[16], rt[16];
    #pragma unroll
    for (int i = 0; i < 16; ++i) { rb[i] = 0u; rs[i] = 0u; rt[i] = 0u; }

    int nb_s = 0, h_s = 1;                      // next phase to stage (ph=1)

    // ---- K-loop: nb (8 strips of 128 k) x h (6 subtiles of 32 dims) ----
    for (int nb = 0; nb < 8; ++nb) {
        f32x4 acc[4][4];
        #pragma unroll
        for (int mt = 0; mt < 4; ++mt)
            #pragma unroll
            for (int nt = 0; nt < 4; ++nt)
                #pragma unroll
                for (int r = 0; r < 4; ++r) acc[mt][nt][r] = 0.f;

        #pragma unroll
        for (int h = 0; h < 6; ++h) {
            const int ph = nb * 6 + h;
            asm volatile("s_waitcnt vmcnt(0)" ::: "memory");  // my stage(ph) done
            __syncthreads();                    // all stages(ph) visible
            if (ph < 47) {                      // stage ph+1 into other half
                const size_t gb = ((size_t)(h_s >> 1) * KCB + nb_s * 128) * 64
                                  + (h_s & 1) * 32;
                async_load16(Bpf + gb + (size_t)sk0 * 64 + sj0 * 8,
                             &Bs[(ph + 1) & 1][tid * 8]);
                async_load16(Bpf + gb + (size_t)sk1 * 64 + sj1 * 8,
                             &Bs[(ph + 1) & 1][(tid + 256) * 8]);
                if (++h_s == 6) { h_s = 0; ++nb_s; }
            }
            const int g = h >> 1, s = h & 1;
            f16x8 af[4], bfr[4];
            #pragma unroll
            for (int mt = 0; mt < 4; ++mt) {
                int m = wm + mt * 16 + l15;
                af[mt] = *(const f16x8*)&As[m * 200 + g * 64 + s * 32 + quad * 8];
            }
            #pragma unroll
            for (int nt = 0; nt < 4; ++nt) {
                int n = wn + nt * 16 + l15;
                bfr[nt] = *(const f16x8*)&Bs[ph & 1][n * 32 + (quad ^ ((n >> 1) & 3)) * 8];
            }
            #pragma unroll
            for (int mt = 0; mt < 4; ++mt)
                #pragma unroll
                for (int nt = 0; nt < 4; ++nt)
                    acc[mt][nt] = __builtin_amdgcn_mfma_f32_16x16x32_f16(
                        af[mt], bfr[nt], acc[mt][nt], 0, 0, 0);
        }

        // per-nb epilogue (overlaps the in-flight stage of next strip):
        // quantize RAW dots; insert into top-3
        int kbase = nb * 128 + wn;
        #pragma unroll
        for (int mt = 0; mt < 4; ++mt) {
            #pragma unroll
            for (int r = 0; r < 4; ++r) {
                const int i = mt * 4 + r;
                #pragma unroll
                for (int nt = 0; nt < 4; ++nt) {
                    unsigned pv = ((unsigned)fmaf(acc[mt][nt][r], 65536.f, 2097152.f) << 10)
                                  | (unsigned)(kbase + nt * 16 + l15);
                    top3_ins(rb[i], rs[i], rt[i], pv);
                }
            }
        }
    }

    // ---- cross-lane / cross-wave top-3 merge ----
    __syncthreads();
    #pragma unroll
    for (int i = 0; i < 16; ++i) {
        unsigned b = rb[i], s = rs[i], t = rt[i];
        #pragma unroll
        for (int off = 1; off < 16; off <<= 1) {
            unsigned ob = __shfl_xor(b, off, 64);
            unsigned os = __shfl_xor(s, off, 64);
            unsigned ot = __shfl_xor(t, off, 64);
            top3_ins(b, s, t, ob);
            top3_ins(b, s, t, os);
            top3_ins(b, s, t, ot);
        }
        if (l15 == 0) {
            int mt = i >> 2, r = i & 3;
            int mloc = wm + mt * 16 + quad * 4 + r;
            t2buf[mloc * 2 + (wave & 1)] = make_uint4(b, s, t, 0u);
        }
    }
    __syncthreads();
    if (tid < 128) {
        uint4 x = t2buf[tid * 2];
        uint4 y = t2buf[tid * 2 + 1];
        unsigned b = x.x, s = x.y, t = x.z;
        top3_ins(b, s, t, y.x);
        top3_ins(b, s, t, y.y);
        top3_ins(b, s, t, y.z);
        sidx[tid] = (int)(b & 1023u);
        unsigned q1 = b >> 10, q2 = s >> 10, q3 = t >> 10;
        unsigned Mq = (unsigned)fmaf(152.0f, nrm_s[tid], 4.0f);
        if (q1 - q3 < Mq) {                     // >=2 rivals in window: full
            int pos = atomicAdd(&scnt_full, 1);
            slist_full[pos] = tid;
        } else if (q1 - q2 < Mq) {              // winner provably in {k1,k2}
            int pos = atomicAdd(&scnt_pair, 1);
            slist_pair[pos] = tid | ((int)(b & 1023u) << 7)
                                  | ((int)(s & 1023u) << 17);
        }
    }
    __syncthreads();
    const int nfull = scnt_full;
    const int npair = scnt_pair;

    // ---- full exact fp32 rescore, 8 points/batch (rare) ----
    {
        float* xsf = (float*)As;                // xs[8][200] overlay
        const float4* ct = (const float4*)cbkT; // [d][256] float4
        const int j8 = tid >> 5, dl = tid & 31;
        for (int base = 0; base < nfull; base += 8) {
            const bool valid = (base + j8) < nfull;
            const int ploc = valid ? slist_full[base + j8] : 0;
            float ss = 0.f;
            if (valid) {
                #pragma unroll
                for (int i = 0; i < 6; ++i) {
                    int d = dl + i * 32;
                    float v = latent[latb + (size_t)d * HW + hw0 + ploc];
                    xsf[j8 * 200 + d] = v;
                    ss = fmaf(v, v, ss);
                }
            }
            part8[j8][dl] = ss;
            if (tid < 8) best8[tid] = ~0ull;
            __syncthreads();
            if (tid < 8) {
                float s = 0.f;
                #pragma unroll
                for (int i = 0; i < 32; ++i) s += part8[tid][i];
                inv8[tid] = 1.0f / (sqrtf(s) + 1e-8f);
            }
            __syncthreads();
            // dots: thread owns codewords 4*tid..4*tid+3 for all 8 points
            float4 a[8];
            #pragma unroll
            for (int p = 0; p < 8; ++p) a[p] = make_float4(0.f, 0.f, 0.f, 0.f);
            for (int d = 0; d < DIMS; d += 4) {
                float4 cv0 = ct[(size_t)(d + 0) * 256 + tid];
                float4 cv1 = ct[(size_t)(d + 1) * 256 + tid];
                float4 cv2 = ct[(size_t)(d + 2) * 256 + tid];
                float4 cv3 = ct[(size_t)(d + 3) * 256 + tid];
                #pragma unroll
                for (int p = 0; p < 8; ++p) {
                    float4 xv = *(const float4*)&xsf[p * 200 + d];
                    a[p].x = fmaf(xv.x, cv0.x, a[p].x); a[p].y = fmaf(xv.x, cv0.y, a[p].y);
                    a[p].z = fmaf(xv.x, cv0.z, a[p].z); a[p].w = fmaf(xv.x, cv0.w, a[p].w);
                    a[p].x = fmaf(xv.y, cv1.x, a[p].x); a[p].y = fmaf(xv.y, cv1.y, a[p].y);
                    a[p].z = fmaf(xv.y, cv1.z, a[p].z); a[p].w = fmaf(xv.y, cv1.w, a[p].w);
                    a[p].x = fmaf(xv.z, cv2.x, a[p].x); a[p].y = fmaf(xv.z, cv2.y, a[p].y);
                    a[p].z = fmaf(xv.z, cv2.z, a[p].z); a[p].w = fmaf(xv.z, cv2.w, a[p].w);
                    a[p].x = fmaf(xv.w, cv3.x, a[p].x); a[p].y = fmaf(xv.w, cv3.y, a[p].y);
                    a[p].z = fmaf(xv.w, cv3.z, a[p].z); a[p].w = fmaf(xv.w, cv3.w, a[p].w);
                }
            }
            #pragma unroll
            for (int p = 0; p < 8; ++p) {
                float inv = inv8[p];
                float dot4[4] = {a[p].x, a[p].y, a[p].z, a[p].w};
                unsigned long long loc = ~0ull;
                #pragma unroll
                for (int e = 0; e < 4; ++e) {
                    int k = 4 * tid + e;
                    float dist = c2[k] - 2.f * inv * dot4[e];
                    unsigned ub = __float_as_uint(dist);
                    ub ^= (ub >> 31) ? 0xFFFFFFFFu : 0x80000000u;   // monotonic
                    unsigned long long pk =
                        ((unsigned long long)ub << 32) | (unsigned)k;
                    loc = loc < pk ? loc : pk;
                }
                #pragma unroll
                for (int off = 1; off < 64; off <<= 1) {
                    unsigned long long o = __shfl_xor(loc, off, 64);
                    loc = loc < o ? loc : o;
                }
                if ((tid & 63) == 0) atomicMin(&best8[p], loc);
            }
            __syncthreads();
            if (valid && dl == 0)
                sidx[ploc] = (int)(best8[j8] & 0xFFFFFFFFull);
            __syncthreads();
        }
    }

    // ---- pair resolution: one thread per flagged pair, exact fp32 ----
    for (int i = tid; i < npair; i += 256) {
        int pk = slist_pair[i];
        int ploc = pk & 127;
        int k1 = (pk >> 7) & 1023;
        int k2 = (pk >> 17) & 1023;
        const float* xr = latent + latb + hw0 + ploc;
        const float* c1 = cbk + (size_t)k1 * DIMS;
        const float* c2r = cbk + (size_t)k2 * DIMS;
        float a1 = 0.f, a2 = 0.f;
        float pp[16];
        #pragma unroll
        for (int e = 0; e < 16; ++e) pp[e] = 0.f;
        for (int d0 = 0; d0 < DIMS; d0 += 16) {
            #pragma unroll
            for (int e = 0; e < 16; ++e) {
                int d = d0 + e;
                float xv = xr[(size_t)d * HW];
                a1 = fmaf(xv, c1[d], a1);
                a2 = fmaf(xv, c2r[d], a2);
                pp[e] = fmaf(xv, xv, pp[e]);
            }
        }
        float ss = 0.f;
        #pragma unroll
        for (int e = 0; e < 16; ++e) ss += pp[e];
        float inv = 1.0f / (sqrtf(ss) + 1e-8f);
        float d1 = c2[k1] - 2.f * inv * a1;
        float d2 = c2[k2] - 2.f * inv * a2;
        unsigned u1 = __float_as_uint(d1);
        u1 ^= (u1 >> 31) ? 0xFFFFFFFFu : 0x80000000u;
        unsigned u2 = __float_as_uint(d2);
        u2 ^= (u2 >> 31) ? 0xFFFFFFFFu : 0x80000000u;
        unsigned long long p1 = ((unsigned long long)u1 << 32) | (unsigned)k1;
        unsigned long long p2 = ((unsigned long long)u2 << 32) | (unsigned)k2;
        sidx[ploc] = (int)((p1 < p2 ? p1 : p2) & 1023ull);
    }
    __syncthreads();

    if (tid < 128) idxf[n0 + tid] = (float)sidx[tid];
    __syncthreads();

    // ---- gather epilogue (q overlays As) ----
    float* q = (float*)As;                      // 32*193*4 = 24.7 KB
    for (int chk = 0; chk < 4; ++chk) {
        int p0 = chk * 32;
        for (int r = wave; r < 32; r += 4) {
            const float* row = cbk + (size_t)sidx[p0 + r] * DIMS;
            for (int c = lane; c < DIMS; c += 64) q[r * 193 + c] = row[c];
        }
        __syncthreads();
        float* ob = out_q + latb + hw0 + p0;
        #pragma unroll
        for (int i = 0; i < 24; ++i) {
            int u = i * 256 + tid;
            int c = u >> 5, p = u & 31;
            ob[(size_t)c * HW + p] = q[p * 193 + c];
        }
        __syncthreads();
    }
}

// ======================= fallback fp32 path (round-1) ====================
__global__ __launch_bounds__(256) void k_norms_fb(const float* __restrict__ latent,
                                                  float* __restrict__ inv_norm) {
    __shared__ float red[256];
    const int tid = threadIdx.x;
    const int n0 = blockIdx.x * 128;
    const int nl = tid & 127;
    const int half = tid >> 7;
    const int b = n0 >> 12;
    const int hw = (n0 & 4095) + nl;
    const float* base = latent + (size_t)b * DIMS * HW + hw;
    float ssq = 0.f;
    for (int c = half; c < DIMS; c += 2) {
        float v = base[(size_t)c * HW];
        ssq = fmaf(v, v, ssq);
    }
    red[tid] = ssq;
    __syncthreads();
    if (half == 0) {
        float s = red[tid] + red[tid + 128];
        inv_norm[n0 + nl] = 1.0f / (sqrtf(s) + 1e-8f);
    }
}

__global__ __launch_bounds__(256) void k_c2_fb(const float* __restrict__ cbk,
                                               float* __restrict__ c2) {
    int k = blockIdx.x * 256 + threadIdx.x;
    if (k >= KCB) return;
    const float4* row = (const float4*)(cbk + (size_t)k * DIMS);
    float s = 0.f;
    #pragma unroll
    for (int i = 0; i < DIMS / 4; ++i) {
        float4 v = row[i];
        s += v.x * v.x + v.y * v.y + v.z * v.z + v.w * v.w;
    }
    c2[k] = s;
}

#define LDX  132
__global__ __launch_bounds__(256) void k_dist_fb(const float* __restrict__ latent,
                                                 const float* __restrict__ cbk,
                                                 const float* __restrict__ inv_norm,
                                                 const float* __restrict__ c2,
                                                 int* __restrict__ idx_out,
                                                 float* __restrict__ idxf_out) {
    __shared__ __align__(16) float xsm[64 * LDX];
    __shared__ __align__(16) float csm[64 * LDX];
    __shared__ unsigned long long red[128];
    const int tid = threadIdx.x;
    const int n0 = blockIdx.x * 128;
    const int b = n0 >> 12;
    const int hw0 = n0 & 4095;
    const int kt = tid & 15;
    const int mt = tid >> 4;
    const float* lat_base = latent + (size_t)b * DIMS * HW + hw0;
    float inv[8];
    #pragma unroll
    for (int i = 0; i < 8; ++i) inv[i] = inv_norm[n0 + mt * 8 + i];
    float best[8];
    int bidx[8];
    #pragma unroll
    for (int i = 0; i < 8; ++i) { best[i] = 3.4e38f; bidx[i] = 0; }
    const int nl = tid & 127;
    const int cp = tid >> 7;
    for (int k0 = 0; k0 < KCB; k0 += 128) {
        float acc[8][8];
        #pragma unroll
        for (int i = 0; i < 8; ++i)
            #pragma unroll
            for (int j = 0; j < 8; ++j) acc[i][j] = 0.f;
        for (int d0 = 0; d0 < DIMS; d0 += 64) {
            __syncthreads();
            for (int cc = cp; cc < 64; cc += 2)
                xsm[cc * LDX + nl] = lat_base[(size_t)(d0 + cc) * HW + nl];
            #pragma unroll
            for (int i = 0; i < 8; ++i) {
                int f4 = tid + 256 * i;
                int kk = f4 >> 4;
                int dq = f4 & 15;
                float4 v = *(const float4*)(cbk + (size_t)(k0 + kk) * DIMS + d0 + dq * 4);
                csm[(dq * 4 + 0) * LDX + kk] = v.x;
                csm[(dq * 4 + 1) * LDX + kk] = v.y;
                csm[(dq * 4 + 2) * LDX + kk] = v.z;
                csm[(dq * 4 + 3) * LDX + kk] = v.w;
            }
            __syncthreads();
            for (int d = 0; d < 64; ++d) {
                const float* xr = &xsm[d * LDX + mt * 8];
                const float* cr = &csm[d * LDX + kt * 8];
                float x8[8], c8[8];
                *(float4*)&x8[0] = *(const float4*)&xr[0];
                *(float4*)&x8[4] = *(const float4*)&xr[4];
                *(float4*)&c8[0] = *(const float4*)&cr[0];
                *(float4*)&c8[4] = *(const float4*)&cr[4];
                #pragma unroll
                for (int i = 0; i < 8; ++i)
                    #pragma unroll
                    for (int j = 0; j < 8; ++j)
                        acc[i][j] = fmaf(x8[i], c8[j], acc[i][j]);
            }
        }
        float cc2[8];
        #pragma unroll
        for (int j = 0; j < 8; ++j) cc2[j] = c2[k0 + kt * 8 + j];
        #pragma unroll
        for (int i = 0; i < 8; ++i)
            #pragma unroll
            for (int j = 0; j < 8; ++j) {
                float t = inv[i] * acc[i][j];
                float dist = fmaf(-2.f, t, cc2[j]);
                int kidx = k0 + kt * 8 + j;
                if (dist < best[i]) { best[i] = dist; bidx[i] = kidx; }
            }
    }
    if (tid < 128) red[tid] = ~0ull;
    __syncthreads();
    #pragma unroll
    for (int i = 0; i < 8; ++i) {
        unsigned long long p =
            ((unsigned long long)__float_as_uint(best[i]) << 32) | (unsigned)bidx[i];
        atomicMin(&red[mt * 8 + i], p);
    }
    __syncthreads();
    if (tid < 128) {
        int k = (int)(red[tid] & 0xFFFFFFFFu);
        idx_out[n0 + tid] = k;
        idxf_out[n0 + tid] = (float)k;
    }
}

__global__ __launch_bounds__(256) void k_gather(const float* __restrict__ cbk,
                                                const int* __restrict__ idx,
                                                float* __restrict__ out) {
    __shared__ float q[64 * 193];
    __shared__ int sidx[64];
    const int tid = threadIdx.x;
    const int n0 = blockIdx.x * 64;
    const int b = n0 >> 12;
    const int hw0 = n0 & 4095;
    const int lane = tid & 63;
    const int grp = tid >> 6;

    if (tid < 64) sidx[tid] = idx[n0 + tid];
    __syncthreads();
    for (int r = grp; r < 64; r += 4) {
        const float* row = cbk + (size_t)sidx[r] * DIMS;
        for (int c = lane; c < DIMS; c += 64) q[r * 193 + c] = row[c];
    }
    __syncthreads();
    float* obase = out + (size_t)b * DIMS * HW + hw0;
    for (int c = grp; c < DIMS; c += 4) {
        obase[(size_t)c * HW + lane] = q[lane * 193 + c];
    }
}

// ================================ launch ================================
extern "C" void kernel_launch(void* const* d_in, const int* in_sizes, int n_in,
                              void* d_out, int out_size, void* d_ws, size_t ws_size,
                              hipStream_t stream) {
    const float* latent = (const float*)d_in[0];
    const float* cbk = (const float*)d_in[1];
    float* out = (float*)d_out;
    float* out_q = out;
    float* out_idx = out + QELEMS;

    if (ws_size >= 2u * 1024u * 1024u) {
        // ws layout (bytes):
        char* w = (char*)d_ws;
        _Float16* Bpf = (_Float16*)w;                          //    393,216
        float* cbkT = (float*)(w + 393216);                    //    786,432
        float* c2 = (float*)(w + 1179648);                     //      4,096

        k_prep<<<KCB / 16, 256, 0, stream>>>(cbk, Bpf, cbkT, c2);
        k_gemm_f<<<512, 256, 0, stream>>>(latent, Bpf, cbkT, c2, cbk,
                                          out_q, out_idx);
    } else {
        float* inv_norm = (float*)d_ws;
        float* c2 = inv_norm + NPTS;
        int* idx = (int*)(c2 + KCB);
        k_norms_fb<<<NPTS / 128, 256, 0, stream>>>(latent, inv_norm);
        k_c2_fb<<<4, 256, 0, stream>>>(cbk, c2);
        k_dist_fb<<<NPTS / 128, 256, 0, stream>>>(latent, cbk, inv_norm, c2, idx, out_idx);
        k_gather<<<NPTS / 64, 256, 0, stream>>>(cbk, idx, out_q);
    }
}

// Round 8
// 191.616 us; speedup vs baseline: 1.6013x; 1.0173x over previous
//
#include <hip/hip_runtime.h>

// Problem: latent (16,192,64,64) fp32, codebook (1024,192) fp32.
// N = 65536 points, D = 192, K = 1024.
// d_out = [quantized: 12582912 fp32][indices-as-float: 65536].

#define NPTS   65536
#define DIMS   192
#define KCB    1024
#define HW     4096
#define QELEMS 12582912

typedef __attribute__((ext_vector_type(8))) _Float16 f16x8;
typedef __attribute__((ext_vector_type(4))) _Float16 f16x4;
typedef __attribute__((ext_vector_type(4))) float f32x4;

// ============================ f16 MFMA path =============================
// Codebook rows are unit-normalized -> argmin dist == argmax dot; inv_norm>0
// per point -> rank RAW dots. q = trunc(fma(dot_raw, 2^16, 2^21)). f16 dot
// error <= 64*||x||+1 q-units, so with Mq = 152*||x||+4:
//  - if q1-q3 >= Mq: true winner is in {k1,k2}; exact fp32 pair compare.
//  - if q1-q3 <  Mq: full exact 1024-codeword rescore (rare).
// K-loop (round-8): depth-2 software pipeline. 48 phases of 8KB subtiles
// (128k x 32d) in a 3-buffer ring; stage(ph+2) issued after the phase
// barrier; raw s_barrier + counted s_waitcnt vmcnt(2) (NOT __syncthreads,
// which drains vmcnt to 0). Exactly 2 global_load_lds per thread per phase,
// no other VMEM in the loop -> the count is exact. vmcnt(0) only at ph=47.

__device__ __forceinline__ void async_load16(const void* g, void* l) {
    __builtin_amdgcn_global_load_lds(
        (const __attribute__((address_space(1))) unsigned int*)g,
        (__attribute__((address_space(3))) unsigned int*)l, 16, 0, 0);
}

// branchless insert of p into sorted top-3 (b >= s >= t)
__device__ __forceinline__ void top3_ins(unsigned& b, unsigned& s, unsigned& t,
                                         unsigned p) {
    unsigned m1 = min(b, p);
    unsigned m2 = min(s, p);
    b = max(b, p);
    s = max(s, m1);
    t = max(t, m2);
}

// ---- fused prep: cbk -> {Bpf f16 group-major [g][k][64], cbkT, c2} ----
// grid 64 x 256; block handles 16 codewords staged once in LDS.
__global__ __launch_bounds__(256) void k_prep(const float* __restrict__ cbk,
                                              _Float16* __restrict__ Bpf,
                                              float* __restrict__ cbkT,
                                              float* __restrict__ c2) {
    __shared__ float q[16 * 193];
    const int tid = threadIdx.x;
    const int k0 = blockIdx.x * 16;
    const int lane = tid & 63;
    const int grp = tid >> 6;
    for (int r = grp; r < 16; r += 4) {
        const float* row = cbk + (size_t)(k0 + r) * DIMS;
        for (int c = lane; c < DIMS; c += 64) q[r * 193 + c] = row[c];
    }
    __syncthreads();
    // fp32 transpose for rescore: 16 lanes of k per dim group
    {
        const int kl = tid & 15, dg = tid >> 4;
        for (int d = dg; d < DIMS; d += 16)
            cbkT[(size_t)d * KCB + k0 + kl] = q[kl * 193 + d];
    }
    // f16 group-major [g][k][64]
    for (int r = grp; r < 16; r += 4)
        for (int c = lane; c < DIMS; c += 64)
            Bpf[((size_t)(c >> 6) * KCB + k0 + r) * 64 + (c & 63)] =
                (_Float16)q[r * 193 + c];
    // row squared norms
    if (tid < 16) {
        float s = 0.f;
        #pragma unroll 4
        for (int c = 0; c < DIMS; ++c) {
            float v = q[tid * 193 + c];
            s = fmaf(v, v, s);
        }
        c2[k0 + tid] = s;
    }
}

// ---- fused: latent->f16 LDS slab + depth-2 ring MFMA + top-3 argmax +
//      cheap exact resolution + gather ----
__global__ __launch_bounds__(256, 2) void k_gemm_f(const float* __restrict__ latent,
                                                   const _Float16* __restrict__ Bpf,
                                                   const float* __restrict__ cbkT,
                                                   const float* __restrict__ c2,
                                                   const float* __restrict__ cbk,
                                                   float* __restrict__ out_q,
                                                   float* __restrict__ idxf) {
    __shared__ __align__(16) _Float16 As[128 * 200];   // 51200 B (overlaid later)
    __shared__ __align__(16) _Float16 Bs[3][4096];     // 3 x 8192 B ring
    __shared__ float nrm_s[128];
    __shared__ float part0[256];

    // post-K-loop overlays into the dead As slab (region [32768, 39616) B;
    // gather q uses [0, 24704), rescore xsf uses [0, 6400) -> no collision)
    char* ovl = (char*)As + 32768;
    uint4* t2buf = (uint4*)ovl;                         // 4096 B
    int* sidx = (int*)(ovl + 4096);                     // 512
    int* slist_pair = (int*)(ovl + 4608);               // 512
    int* slist_full = (int*)(ovl + 5120);               // 512
    int* scnts = (int*)(ovl + 5632);                    // [0]=pair [1]=full
    float* part8 = (float*)(ovl + 5696);                // [8][32] flat
    float* inv8 = (float*)(ovl + 6720);                 // 32
    unsigned long long* best8 = (unsigned long long*)(ovl + 6784);  // 64

    const int tid = threadIdx.x;
    const int wave = tid >> 6;
    const int lane = tid & 63;
    const int quad = lane >> 4;
    const int l15 = lane & 15;
    const int wm = (wave >> 1) * 64;
    const int wn = (wave & 1) * 64;
    const int n0 = blockIdx.x * 128;
    const int bB = n0 >> 12;
    const int hw0 = n0 & 4095;
    const size_t latb = (size_t)bB * DIMS * HW;

    // staging constants: thread stages 16B-units {tid, tid+256} of 512.
    // Subtile = 128 k x 32 dims; swizzle j_src = j_phys ^ ((k>>1)&3).
    const int sk0 = tid >> 2,         sj0 = (tid & 3) ^ ((sk0 >> 1) & 3);
    const int sk1 = (tid + 256) >> 2, sj1 = ((tid + 256) & 3) ^ ((sk1 >> 1) & 3);

    // prologue: stage phases 0 (g0,s0) and 1 (g0,s1); they land during phase 0
    async_load16(Bpf + (size_t)sk0 * 64 + sj0 * 8, &Bs[0][tid * 8]);
    async_load16(Bpf + (size_t)sk1 * 64 + sj1 * 8, &Bs[0][(tid + 256) * 8]);
    async_load16(Bpf + (size_t)sk0 * 64 + sj0 * 8 + 32, &Bs[1][tid * 8]);
    async_load16(Bpf + (size_t)sk1 * 64 + sj1 * 8 + 32, &Bs[1][(tid + 256) * 8]);

    // ---- phase 0: load raw latent slab once, f16-convert, ssq ----
    {
        const float* lat = latent + latb + hw0;
        const int p = tid & 127, ch = tid >> 7;
        float ss = 0.f;
        #pragma unroll 4
        for (int i = 0; i < 24; ++i) {
            int c0 = i * 8 + ch * 4;
            float v0 = lat[(size_t)(c0 + 0) * HW + p];
            float v1 = lat[(size_t)(c0 + 1) * HW + p];
            float v2 = lat[(size_t)(c0 + 2) * HW + p];
            float v3 = lat[(size_t)(c0 + 3) * HW + p];
            ss = fmaf(v0, v0, fmaf(v1, v1, fmaf(v2, v2, fmaf(v3, v3, ss))));
            f16x4 h = { (_Float16)v0, (_Float16)v1, (_Float16)v2, (_Float16)v3 };
            *(f16x4*)&As[p * 200 + c0] = h;
        }
        part0[ch * 128 + p] = ss;
        __syncthreads();
        if (tid < 128)
            nrm_s[tid] = sqrtf(part0[tid] + part0[128 + tid]);
        __syncthreads();
    }

    unsigned rb[16], rs[16], rt[16];
    #pragma unroll
    for (int i = 0; i < 16; ++i) { rb[i] = 0u; rs[i] = 0u; rt[i] = 0u; }

    int bc = 0;                     // ring slot of current phase
    int nb_s = 0, h_s = 2;          // source coords of next stage (ph+2)

    // ---- K-loop: nb (8 strips of 128 k) x h (6 subtiles of 32 dims) ----
    for (int nb = 0; nb < 8; ++nb) {
        f32x4 acc[4][4];
        #pragma unroll
        for (int mt = 0; mt < 4; ++mt)
            #pragma unroll
            for (int nt = 0; nt < 4; ++nt)
                #pragma unroll
                for (int r = 0; r < 4; ++r) acc[mt][nt][r] = 0.f;

        #pragma unroll
        for (int h = 0; h < 6; ++h) {
            // wait for stage(ph): keep stage(ph+1) [2 loads] in flight
            if (nb == 7 && h == 5) {
                asm volatile("s_waitcnt vmcnt(0)" ::: "memory");
            } else {
                asm volatile("s_waitcnt vmcnt(2)" ::: "memory");
            }
            __builtin_amdgcn_s_barrier();       // all waves' stage(ph) visible
            asm volatile("" ::: "memory");
            // stage(ph+2) into slot bc+2 (its readers finished phase ph-1)
            if (!(nb == 7 && h >= 4)) {
                const int bt = (bc >= 1) ? bc - 1 : bc + 2;
                const size_t gb = ((size_t)(h_s >> 1) * KCB + nb_s * 128) * 64
                                  + (h_s & 1) * 32;
                async_load16(Bpf + gb + (size_t)sk0 * 64 + sj0 * 8,
                             &Bs[bt][tid * 8]);
                async_load16(Bpf + gb + (size_t)sk1 * 64 + sj1 * 8,
                             &Bs[bt][(tid + 256) * 8]);
                if (++h_s == 6) { h_s = 0; ++nb_s; }
            }
            const int g = h >> 1, s = h & 1;
            f16x8 af[4], bfr[4];
            #pragma unroll
            for (int mt = 0; mt < 4; ++mt) {
                int m = wm + mt * 16 + l15;
                af[mt] = *(const f16x8*)&As[m * 200 + g * 64 + s * 32 + quad * 8];
            }
            #pragma unroll
            for (int nt = 0; nt < 4; ++nt) {
                int n = wn + nt * 16 + l15;
                bfr[nt] = *(const f16x8*)&Bs[bc][n * 32 + (quad ^ ((n >> 1) & 3)) * 8];
            }
            #pragma unroll
            for (int mt = 0; mt < 4; ++mt)
                #pragma unroll
                for (int nt = 0; nt < 4; ++nt)
                    acc[mt][nt] = __builtin_amdgcn_mfma_f32_16x16x32_f16(
                        af[mt], bfr[nt], acc[mt][nt], 0, 0, 0);
            bc = (bc == 2) ? 0 : bc + 1;
        }

        // per-nb epilogue (overlaps in-flight stages): top-3 insert
        int kbase = nb * 128 + wn;
        #pragma unroll
        for (int mt = 0; mt < 4; ++mt) {
            #pragma unroll
            for (int r = 0; r < 4; ++r) {
                const int i = mt * 4 + r;
                #pragma unroll
                for (int nt = 0; nt < 4; ++nt) {
                    unsigned pv = ((unsigned)fmaf(acc[mt][nt][r], 65536.f, 2097152.f) << 10)
                                  | (unsigned)(kbase + nt * 16 + l15);
                    top3_ins(rb[i], rs[i], rt[i], pv);
                }
            }
        }
    }

    // ---- cross-lane / cross-wave top-3 merge (As now dead -> overlays ok) ----
    __syncthreads();
    if (tid == 0) { scnts[0] = 0; scnts[1] = 0; }
    #pragma unroll
    for (int i = 0; i < 16; ++i) {
        unsigned b = rb[i], s = rs[i], t = rt[i];
        #pragma unroll
        for (int off = 1; off < 16; off <<= 1) {
            unsigned ob = __shfl_xor(b, off, 64);
            unsigned os = __shfl_xor(s, off, 64);
            unsigned ot = __shfl_xor(t, off, 64);
            top3_ins(b, s, t, ob);
            top3_ins(b, s, t, os);
            top3_ins(b, s, t, ot);
        }
        if (l15 == 0) {
            int mt = i >> 2, r = i & 3;
            int mloc = wm + mt * 16 + quad * 4 + r;
            t2buf[mloc * 2 + (wave & 1)] = make_uint4(b, s, t, 0u);
        }
    }
    __syncthreads();
    if (tid < 128) {
        uint4 x = t2buf[tid * 2];
        uint4 y = t2buf[tid * 2 + 1];
        unsigned b = x.x, s = x.y, t = x.z;
        top3_ins(b, s, t, y.x);
        top3_ins(b, s, t, y.y);
        top3_ins(b, s, t, y.z);
        sidx[tid] = (int)(b & 1023u);
        unsigned q1 = b >> 10, q2 = s >> 10, q3 = t >> 10;
        unsigned Mq = (unsigned)fmaf(152.0f, nrm_s[tid], 4.0f);
        if (q1 - q3 < Mq) {                     // >=2 rivals in window: full
            int pos = atomicAdd(&scnts[1], 1);
            slist_full[pos] = tid;
        } else if (q1 - q2 < Mq) {              // winner provably in {k1,k2}
            int pos = atomicAdd(&scnts[0], 1);
            slist_pair[pos] = tid | ((int)(b & 1023u) << 7)
                                  | ((int)(s & 1023u) << 17);
        }
    }
    __syncthreads();
    const int nfull = scnts[1];
    const int npair = scnts[0];

    // ---- full exact fp32 rescore, 8 points/batch (rare) ----
    {
        float* xsf = (float*)As;                // xs[8][200] overlay
        const float4* ct = (const float4*)cbkT; // [d][256] float4
        const int j8 = tid >> 5, dl = tid & 31;
        for (int base = 0; base < nfull; base += 8) {
            const bool valid = (base + j8) < nfull;
            const int ploc = valid ? slist_full[base + j8] : 0;
            float ss = 0.f;
            if (valid) {
                #pragma unroll
                for (int i = 0; i < 6; ++i) {
                    int d = dl + i * 32;
                    float v = latent[latb + (size_t)d * HW + hw0 + ploc];
                    xsf[j8 * 200 + d] = v;
                    ss = fmaf(v, v, ss);
                }
            }
            part8[j8 * 32 + dl] = ss;
            if (tid < 8) best8[tid] = ~0ull;
            __syncthreads();
            if (tid < 8) {
                float s = 0.f;
                #pragma unroll
                for (int i = 0; i < 32; ++i) s += part8[tid * 32 + i];
                inv8[tid] = 1.0f / (sqrtf(s) + 1e-8f);
            }
            __syncthreads();
            // dots: thread owns codewords 4*tid..4*tid+3 for all 8 points
            float4 a[8];
            #pragma unroll
            for (int p = 0; p < 8; ++p) a[p] = make_float4(0.f, 0.f, 0.f, 0.f);
            for (int d = 0; d < DIMS; d += 4) {
                float4 cv0 = ct[(size_t)(d + 0) * 256 + tid];
                float4 cv1 = ct[(size_t)(d + 1) * 256 + tid];
                float4 cv2 = ct[(size_t)(d + 2) * 256 + tid];
                float4 cv3 = ct[(size_t)(d + 3) * 256 + tid];
                #pragma unroll
                for (int p = 0; p < 8; ++p) {
                    float4 xv = *(const float4*)&xsf[p * 200 + d];
                    a[p].x = fmaf(xv.x, cv0.x, a[p].x); a[p].y = fmaf(xv.x, cv0.y, a[p].y);
                    a[p].z = fmaf(xv.x, cv0.z, a[p].z); a[p].w = fmaf(xv.x, cv0.w, a[p].w);
                    a[p].x = fmaf(xv.y, cv1.x, a[p].x); a[p].y = fmaf(xv.y, cv1.y, a[p].y);
                    a[p].z = fmaf(xv.y, cv1.z, a[p].z); a[p].w = fmaf(xv.y, cv1.w, a[p].w);
                    a[p].x = fmaf(xv.z, cv2.x, a[p].x); a[p].y = fmaf(xv.z, cv2.y, a[p].y);
                    a[p].z = fmaf(xv.z, cv2.z, a[p].z); a[p].w = fmaf(xv.z, cv2.w, a[p].w);
                    a[p].x = fmaf(xv.w, cv3.x, a[p].x); a[p].y = fmaf(xv.w, cv3.y, a[p].y);
                    a[p].z = fmaf(xv.w, cv3.z, a[p].z); a[p].w = fmaf(xv.w, cv3.w, a[p].w);
                }
            }
            #pragma unroll
            for (int p = 0; p < 8; ++p) {
                float inv = inv8[p];
                float dot4[4] = {a[p].x, a[p].y, a[p].z, a[p].w};
                unsigned long long loc = ~0ull;
                #pragma unroll
                for (int e = 0; e < 4; ++e) {
                    int k = 4 * tid + e;
                    float dist = c2[k] - 2.f * inv * dot4[e];
                    unsigned ub = __float_as_uint(dist);
                    ub ^= (ub >> 31) ? 0xFFFFFFFFu : 0x80000000u;   // monotonic
                    unsigned long long pk =
                        ((unsigned long long)ub << 32) | (unsigned)k;
                    loc = loc < pk ? loc : pk;
                }
                #pragma unroll
                for (int off = 1; off < 64; off <<= 1) {
                    unsigned long long o = __shfl_xor(loc, off, 64);
                    loc = loc < o ? loc : o;
                }
                if ((tid & 63) == 0) atomicMin(&best8[p], loc);
            }
            __syncthreads();
            if (valid && dl == 0)
                sidx[ploc] = (int)(best8[j8] & 0xFFFFFFFFull);
            __syncthreads();
        }
    }

    // ---- pair resolution: one thread per flagged pair, exact fp32 ----
    for (int i = tid; i < npair; i += 256) {
        int pk = slist_pair[i];
        int ploc = pk & 127;
        int k1 = (pk >> 7) & 1023;
        int k2 = (pk >> 17) & 1023;
        const float* xr = latent + latb + hw0 + ploc;
        const float* c1 = cbk + (size_t)k1 * DIMS;
        const float* c2r = cbk + (size_t)k2 * DIMS;
        float a1 = 0.f, a2 = 0.f;
        float pp[16];
        #pragma unroll
        for (int e = 0; e < 16; ++e) pp[e] = 0.f;
        for (int d0 = 0; d0 < DIMS; d0 += 16) {
            #pragma unroll
            for (int e = 0; e < 16; ++e) {
                int d = d0 + e;
                float xv = xr[(size_t)d * HW];
                a1 = fmaf(xv, c1[d], a1);
                a2 = fmaf(xv, c2r[d], a2);
                pp[e] = fmaf(xv, xv, pp[e]);
            }
        }
        float ss = 0.f;
        #pragma unroll
        for (int e = 0; e < 16; ++e) ss += pp[e];
        float inv = 1.0f / (sqrtf(ss) + 1e-8f);
        float d1 = c2[k1] - 2.f * inv * a1;
        float d2 = c2[k2] - 2.f * inv * a2;
        unsigned u1 = __float_as_uint(d1);
        u1 ^= (u1 >> 31) ? 0xFFFFFFFFu : 0x80000000u;
        unsigned u2 = __float_as_uint(d2);
        u2 ^= (u2 >> 31) ? 0xFFFFFFFFu : 0x80000000u;
        unsigned long long p1 = ((unsigned long long)u1 << 32) | (unsigned)k1;
        unsigned long long p2 = ((unsigned long long)u2 << 32) | (unsigned)k2;
        sidx[ploc] = (int)((p1 < p2 ? p1 : p2) & 1023ull);
    }
    __syncthreads();

    if (tid < 128) idxf[n0 + tid] = (float)sidx[tid];
    __syncthreads();

    // ---- gather epilogue (q overlays As[0..24704)) ----
    float* q = (float*)As;
    for (int chk = 0; chk < 4; ++chk) {
        int p0 = chk * 32;
        for (int r = wave; r < 32; r += 4) {
            const float* row = cbk + (size_t)sidx[p0 + r] * DIMS;
            for (int c = lane; c < DIMS; c += 64) q[r * 193 + c] = row[c];
        }
        __syncthreads();
        float* ob = out_q + latb + hw0 + p0;
        #pragma unroll
        for (int i = 0; i < 24; ++i) {
            int u = i * 256 + tid;
            int c = u >> 5, p = u & 31;
            ob[(size_t)c * HW + p] = q[p * 193 + c];
        }
        __syncthreads();
    }
}

// ======================= fallback fp32 path (round-1) ====================
__global__ __launch_bounds__(256) void k_norms_fb(const float* __restrict__ latent,
                                                  float* __restrict__ inv_norm) {
    __shared__ float red[256];
    const int tid = threadIdx.x;
    const int n0 = blockIdx.x * 128;
    const int nl = tid & 127;
    const int half = tid >> 7;
    const int b = n0 >> 12;
    const int hw = (n0 & 4095) + nl;
    const float* base = latent + (size_t)b * DIMS * HW + hw;
    float ssq = 0.f;
    for (int c = half; c < DIMS; c += 2) {
        float v = base[(size_t)c * HW];
        ssq = fmaf(v, v, ssq);
    }
    red[tid] = ssq;
    __syncthreads();
    if (half == 0) {
        float s = red[tid] + red[tid + 128];
        inv_norm[n0 + nl] = 1.0f / (sqrtf(s) + 1e-8f);
    }
}

__global__ __launch_bounds__(256) void k_c2_fb(const float* __restrict__ cbk,
                                               float* __restrict__ c2) {
    int k = blockIdx.x * 256 + threadIdx.x;
    if (k >= KCB) return;
    const float4* row = (const float4*)(cbk + (size_t)k * DIMS);
    float s = 0.f;
    #pragma unroll
    for (int i = 0; i < DIMS / 4; ++i) {
        float4 v = row[i];
        s += v.x * v.x + v.y * v.y + v.z * v.z + v.w * v.w;
    }
    c2[k] = s;
}

#define LDX  132
__global__ __launch_bounds__(256) void k_dist_fb(const float* __restrict__ latent,
                                                 const float* __restrict__ cbk,
                                                 const float* __restrict__ inv_norm,
                                                 const float* __restrict__ c2,
                                                 int* __restrict__ idx_out,
                                                 float* __restrict__ idxf_out) {
    __shared__ __align__(16) float xsm[64 * LDX];
    __shared__ __align__(16) float csm[64 * LDX];
    __shared__ unsigned long long red[128];
    const int tid = threadIdx.x;
    const int n0 = blockIdx.x * 128;
    const int b = n0 >> 12;
    const int hw0 = n0 & 4095;
    const int kt = tid & 15;
    const int mt = tid >> 4;
    const float* lat_base = latent + (size_t)b * DIMS * HW + hw0;
    float inv[8];
    #pragma unroll
    for (int i = 0; i < 8; ++i) inv[i] = inv_norm[n0 + mt * 8 + i];
    float best[8];
    int bidx[8];
    #pragma unroll
    for (int i = 0; i < 8; ++i) { best[i] = 3.4e38f; bidx[i] = 0; }
    const int nl = tid & 127;
    const int cp = tid >> 7;
    for (int k0 = 0; k0 < KCB; k0 += 128) {
        float acc[8][8];
        #pragma unroll
        for (int i = 0; i < 8; ++i)
            #pragma unroll
            for (int j = 0; j < 8; ++j) acc[i][j] = 0.f;
        for (int d0 = 0; d0 < DIMS; d0 += 64) {
            __syncthreads();
            for (int cc = cp; cc < 64; cc += 2)
                xsm[cc * LDX + nl] = lat_base[(size_t)(d0 + cc) * HW + nl];
            #pragma unroll
            for (int i = 0; i < 8; ++i) {
                int f4 = tid + 256 * i;
                int kk = f4 >> 4;
                int dq = f4 & 15;
                float4 v = *(const float4*)(cbk + (size_t)(k0 + kk) * DIMS + d0 + dq * 4);
                csm[(dq * 4 + 0) * LDX + kk] = v.x;
                csm[(dq * 4 + 1) * LDX + kk] = v.y;
                csm[(dq * 4 + 2) * LDX + kk] = v.z;
                csm[(dq * 4 + 3) * LDX + kk] = v.w;
            }
            __syncthreads();
            for (int d = 0; d < 64; ++d) {
                const float* xr = &xsm[d * LDX + mt * 8];
                const float* cr = &csm[d * LDX + kt * 8];
                float x8[8], c8[8];
                *(float4*)&x8[0] = *(const float4*)&xr[0];
                *(float4*)&x8[4] = *(const float4*)&xr[4];
                *(float4*)&c8[0] = *(const float4*)&cr[0];
                *(float4*)&c8[4] = *(const float4*)&cr[4];
                #pragma unroll
                for (int i = 0; i < 8; ++i)
                    #pragma unroll
                    for (int j = 0; j < 8; ++j)
                        acc[i][j] = fmaf(x8[i], c8[j], acc[i][j]);
            }
        }
        float cc2[8];
        #pragma unroll
        for (int j = 0; j < 8; ++j) cc2[j] = c2[k0 + kt * 8 + j];
        #pragma unroll
        for (int i = 0; i < 8; ++i)
            #pragma unroll
            for (int j = 0; j < 8; ++j) {
                float t = inv[i] * acc[i][j];
                float dist = fmaf(-2.f, t, cc2[j]);
                int kidx = k0 + kt * 8 + j;
                if (dist < best[i]) { best[i] = dist; bidx[i] = kidx; }
            }
    }
    if (tid < 128) red[tid] = ~0ull;
    __syncthreads();
    #pragma unroll
    for (int i = 0; i < 8; ++i) {
        unsigned long long p =
            ((unsigned long long)__float_as_uint(best[i]) << 32) | (unsigned)bidx[i];
        atomicMin(&red[mt * 8 + i], p);
    }
    __syncthreads();
    if (tid < 128) {
        int k = (int)(red[tid] & 0xFFFFFFFFu);
        idx_out[n0 + tid] = k;
        idxf_out[n0 + tid] = (float)k;
    }
}

__global__ __launch_bounds__(256) void k_gather(const float* __restrict__ cbk,
                                                const int* __restrict__ idx,
                                                float* __restrict__ out) {
    __shared__ float q[64 * 193];
    __shared__ int sidx[64];
    const int tid = threadIdx.x;
    const int n0 = blockIdx.x * 64;
    const int b = n0 >> 12;
    const int hw0 = n0 & 4095;
    const int lane = tid & 63;
    const int grp = tid >> 6;

    if (tid < 64) sidx[tid] = idx[n0 + tid];
    __syncthreads();
    for (int r = grp; r < 64; r += 4) {
        const float* row = cbk + (size_t)sidx[r] * DIMS;
        for (int c = lane; c < DIMS; c += 64) q[r * 193 + c] = row[c];
    }
    __syncthreads();
    float* obase = out + (size_t)b * DIMS * HW + hw0;
    for (int c = grp; c < DIMS; c += 4) {
        obase[(size_t)c * HW + lane] = q[lane * 193 + c];
    }
}

// ================================ launch ================================
extern "C" void kernel_launch(void* const* d_in, const int* in_sizes, int n_in,
                              void* d_out, int out_size, void* d_ws, size_t ws_size,
                              hipStream_t stream) {
    const float* latent = (const float*)d_in[0];
    const float* cbk = (const float*)d_in[1];
    float* out = (float*)d_out;
    float* out_q = out;
    float* out_idx = out + QELEMS;

    if (ws_size >= 2u * 1024u * 1024u) {
        // ws layout (bytes):
        char* w = (char*)d_ws;
        _Float16* Bpf = (_Float16*)w;                          //    393,216
        float* cbkT = (float*)(w + 393216);                    //    786,432
        float* c2 = (float*)(w + 1179648);                     //      4,096

        k_prep<<<KCB / 16, 256, 0, stream>>>(cbk, Bpf, cbkT, c2);
        k_gemm_f<<<512, 256, 0, stream>>>(latent, Bpf, cbkT, c2, cbk,
                                          out_q, out_idx);
    } else {
        float* inv_norm = (float*)d_ws;
        float* c2 = inv_norm + NPTS;
        int* idx = (int*)(c2 + KCB);
        k_norms_fb<<<NPTS / 128, 256, 0, stream>>>(latent, inv_norm);
        k_c2_fb<<<4, 256, 0, stream>>>(cbk, c2);
        k_dist_fb<<<NPTS / 128, 256, 0, stream>>>(latent, cbk, inv_norm, c2, idx, out_idx);
        k_gather<<<NPTS / 64, 256, 0, stream>>>(cbk, idx, out_q);
    }
}